// Round 2
// baseline (811.414 us; speedup 1.0000x reference)
//
#include <hip/hip_runtime.h>
#include <hip/hip_bf16.h>

typedef __bf16 bf16_t;
typedef __bf16 bf16x8 __attribute__((ext_vector_type(8)));
typedef float f32x4 __attribute__((ext_vector_type(4)));

// Problem constants
#define T_SEQ 3072
#define DIM 2048
#define NH 16
#define QLORA 1536
#define KVLORA 512
#define NOPE 128
#define ROPE 64
#define VDIM 128
#define HD 192          // NOPE+ROPE
#define SCALE 0.07216878364870323f  // 192^-0.5
#define CHUNK 12        // k-tiles (of 64 keys) per attention block

// ---------------- helpers ----------------
__device__ inline float wave_reduce_sum(float v) {
    #pragma unroll
    for (int off = 32; off > 0; off >>= 1) v += __shfl_down(v, off);
    return v;
}

__device__ inline float block_reduce_sum_256(float v) {
    __shared__ float red[4];
    int lane = threadIdx.x & 63, w = threadIdx.x >> 6;
    v = wave_reduce_sum(v);
    if (lane == 0) red[w] = v;
    __syncthreads();
    if (threadIdx.x == 0) red[0] = red[0] + red[1] + red[2] + red[3];
    __syncthreads();
    return red[0];
}

// async global->LDS, 16B per lane. LDS dest must be linear: wave-uniform base + lane*16.
__device__ inline void glds16(const bf16_t* g, bf16_t* l) {
    __builtin_amdgcn_global_load_lds(
        (const __attribute__((address_space(1))) unsigned int*)g,
        (__attribute__((address_space(3))) unsigned int*)l, 16, 0, 0);
}

// ---------------- fp32 -> bf16 convert ----------------
__global__ void f2b_kernel(const float* __restrict__ in, bf16_t* __restrict__ out, int n) {
    int i = (blockIdx.x * 256 + threadIdx.x) * 4;
    if (i < n) {
        float4 v = *(const float4*)&in[i];
        bf16_t o[4] = {(bf16_t)v.x, (bf16_t)v.y, (bf16_t)v.z, (bf16_t)v.w};
        *(uint2*)&out[i] = *(const uint2*)o;
    }
}

// ---------------- fp32 [K][N] -> bf16 [N][K] transpose-convert ----------------
__global__ __launch_bounds__(256) void transp_kernel(
    const float* __restrict__ in, bf16_t* __restrict__ out, int K, int N)
{
    __shared__ float tile[32][33];
    int k0 = blockIdx.y * 32, n0 = blockIdx.x * 32;
    int tx = threadIdx.x & 31, ty = threadIdx.x >> 5;
    #pragma unroll
    for (int i = 0; i < 4; ++i)
        tile[ty + i * 8][tx] = in[(size_t)(k0 + ty + i * 8) * N + n0 + tx];
    __syncthreads();
    #pragma unroll
    for (int i = 0; i < 4; ++i)
        out[(size_t)(n0 + ty + i * 8) * K + k0 + tx] = (bf16_t)tile[tx][ty + i * 8];
}

// ---------------- bf16 kvu V-part -> vt[h][d][t] transpose ----------------
__global__ __launch_bounds__(256) void vt_transp(
    const bf16_t* __restrict__ kvu, bf16_t* __restrict__ vt)
{
    __shared__ bf16_t tile[32][34];
    int t0 = blockIdx.x * 32, d0 = blockIdx.y * 32, h = blockIdx.z;
    int tx = threadIdx.x & 31, ty = threadIdx.x >> 5;
    #pragma unroll
    for (int i = 0; i < 4; ++i)
        tile[ty + i * 8][tx] = kvu[(size_t)(t0 + ty + i * 8) * (NH * 256) + h * 256 + NOPE + d0 + tx];
    __syncthreads();
    #pragma unroll
    for (int i = 0; i < 4; ++i)
        vt[((size_t)h * VDIM + d0 + ty + i * 8) * T_SEQ + t0 + tx] = tile[tx][ty + i * 8];
}

// ---------------- MFMA GEMM (m97 structure): C[M,N] = A[M,K](bf16) x Bt[N,K](bf16) ----------------
// 128x128 tile, BK=32, linear LDS staged via global_load_lds width=16.
__global__ __launch_bounds__(256) void gemm_mfma(
    const bf16_t* __restrict__ A, const bf16_t* __restrict__ Bt,
    float* __restrict__ Cf, bf16_t* __restrict__ Cb,
    int M, int N, int K, int writef)
{
    __shared__ __align__(16) bf16_t As[128 * 32];
    __shared__ __align__(16) bf16_t Bs[128 * 32];
    int tid = threadIdx.x;
    int w = tid >> 6, lane = tid & 63;
    int quad = lane >> 4, l16 = lane & 15;
    int bm = blockIdx.y * 128, bn = blockIdx.x * 128;
    int wm = (w & 1) * 64, wn = (w >> 1) * 64;

    // staging coords: thread stages rows srow and srow+64, 16B chunk soff
    int srow = tid >> 2, soff = (tid & 3) * 8;
    const bf16_t* a0 = A + (size_t)(bm + srow) * K + soff;
    const bf16_t* a1 = A + (size_t)(bm + 64 + srow) * K + soff;
    int br0 = bn + srow;      if (br0 >= N) br0 = N - 1;   // clamp (cols >= N never written)
    int br1 = bn + 64 + srow; if (br1 >= N) br1 = N - 1;
    const bf16_t* b0 = Bt + (size_t)br0 * K + soff;
    const bf16_t* b1 = Bt + (size_t)br1 * K + soff;
    bf16_t* la = &As[tid * 8];   // byte off = tid*16 = wave_base + lane*16
    bf16_t* lb = &Bs[tid * 8];

    f32x4 acc[4][4];
    #pragma unroll
    for (int i = 0; i < 4; ++i)
        #pragma unroll
        for (int j = 0; j < 4; ++j)
            acc[i][j] = (f32x4){0.f, 0.f, 0.f, 0.f};

    for (int k0 = 0; k0 < K; k0 += 32) {
        glds16(a0 + k0, la);
        glds16(a1 + k0, la + 2048);
        glds16(b0 + k0, lb);
        glds16(b1 + k0, lb + 2048);
        __syncthreads();   // compiler drains vmcnt before s_barrier
        bf16x8 af[4], bfr[4];
        #pragma unroll
        for (int t = 0; t < 4; ++t) {
            af[t]  = *(const bf16x8*)&As[(wm + t * 16 + l16) * 32 + quad * 8];
            bfr[t] = *(const bf16x8*)&Bs[(wn + t * 16 + l16) * 32 + quad * 8];
        }
        #pragma unroll
        for (int i = 0; i < 4; ++i)
            #pragma unroll
            for (int j = 0; j < 4; ++j)
                acc[i][j] = __builtin_amdgcn_mfma_f32_16x16x32_bf16(af[i], bfr[j], acc[i][j], 0, 0, 0);
        __syncthreads();
    }

    #pragma unroll
    for (int i = 0; i < 4; ++i) {
        #pragma unroll
        for (int j = 0; j < 4; ++j) {
            #pragma unroll
            for (int r = 0; r < 4; ++r) {
                int row = bm + wm + i * 16 + quad * 4 + r;
                int col = bn + wn + j * 16 + l16;
                if (col < N) {
                    if (writef) Cf[(size_t)row * N + col] = acc[i][j][r];
                    else        Cb[(size_t)row * N + col] = (bf16_t)acc[i][j][r];
                }
            }
        }
    }
}

// ---------------- rmsnorm in-place over rows ----------------
__global__ __launch_bounds__(256) void rmsnorm_rows(
    bf16_t* __restrict__ X, const float* __restrict__ w, int N)
{
    int row = blockIdx.x;
    bf16_t* x = X + (size_t)row * N;
    float ss = 0.f;
    for (int i = threadIdx.x; i < N; i += 256) { float v = (float)x[i]; ss += v * v; }
    ss = block_reduce_sum_256(ss);
    float sc = rsqrtf(ss / (float)N + 1e-6f);
    for (int i = threadIdx.x; i < N; i += 256)
        x[i] = (bf16_t)((float)x[i] * sc * w[i]);
}

// ---------------- kv post ----------------
__global__ __launch_bounds__(256) void kv_post(
    const bf16_t* __restrict__ kvd, const float* __restrict__ w,
    const float* __restrict__ freqs,
    bf16_t* __restrict__ ckvn, bf16_t* __restrict__ kr)
{
    int row = blockIdx.x;
    const bf16_t* src = kvd + (size_t)row * (KVLORA + ROPE);
    float ss = 0.f;
    for (int i = threadIdx.x; i < KVLORA; i += 256) { float v = (float)src[i]; ss += v * v; }
    ss = block_reduce_sum_256(ss);
    float sc = rsqrtf(ss / (float)KVLORA + 1e-6f);
    for (int i = threadIdx.x; i < KVLORA; i += 256)
        ckvn[(size_t)row * KVLORA + i] = (bf16_t)((float)src[i] * sc * w[i]);
    if (threadIdx.x < 32) {
        int i = threadIdx.x;
        float f = freqs[row * 32 + i];
        float c = cosf(f), s = sinf(f);
        float x1 = (float)src[KVLORA + 2 * i], x2 = (float)src[KVLORA + 2 * i + 1];
        kr[(size_t)row * ROPE + 2 * i]     = (bf16_t)(x1 * c - x2 * s);
        kr[(size_t)row * ROPE + 2 * i + 1] = (bf16_t)(x1 * s + x2 * c);
    }
}

// ---------------- rope on q_rope in-place ----------------
__global__ void rope_q(bf16_t* __restrict__ qr, const float* __restrict__ freqs) {
    int idx = blockIdx.x * 256 + threadIdx.x;
    if (idx >= T_SEQ * NH * 32) return;
    int t = idx >> 9;
    int rem = idx & 511;
    int h = rem >> 5;
    int i = rem & 31;
    float f = freqs[t * 32 + i];
    float c = cosf(f), s = sinf(f);
    bf16_t* p = qr + (size_t)t * (NH * ROPE) + h * ROPE + 2 * i;
    float x1 = (float)p[0], x2 = (float)p[1];
    p[0] = (bf16_t)(x1 * c - x2 * s);
    p[1] = (bf16_t)(x1 * s + x2 * c);
}

// ---------------- split-K MFMA flash attention (causal, fixed-max softmax) ----------------
// v6: same structure as v5 (LDS-staged V, reg-prefetch double buffering) but NO
// occupancy clause in launch_bounds -- the (256,3) bound forced VGPR<=80 and the
// ~160 live regs spilled to scratch (WRITE_SIZE 31MB->703MB, the whole regression).
#define KS_STRIDE 200   // 192+8 bf16
#define VS_STRIDE 72    // 64+8 bf16
#define P_STRIDE 72     // 64+8 bf16
__device__ inline int slot_base(int qt, int h) {
    int b = qt / CHUNK;
    return h * 120 + qt + 6 * b * (b - 1) + (qt - CHUNK * b) * b;
}
__global__ __launch_bounds__(256) void attn_v6(
    const bf16_t* __restrict__ QN, const bf16_t* __restrict__ QR,
    const bf16_t* __restrict__ KVU, const bf16_t* __restrict__ KR,
    const bf16_t* __restrict__ Vt,
    bf16_t* __restrict__ Opart, float* __restrict__ lpart)
{
    __shared__ __align__(16) bf16_t Ks[64 * KS_STRIDE];   // 25600 B
    __shared__ __align__(16) bf16_t Vs[128 * VS_STRIDE];  // 18432 B
    __shared__ __align__(16) bf16_t Ps[4][16 * P_STRIDE]; //  9216 B

    int qt = blockIdx.x, cx = blockIdx.y, h = blockIdx.z;
    if (cx > qt / CHUNK) return;
    int slot = slot_base(qt, h) + cx;
    int kt0 = cx * CHUNK;
    int kt1 = min(qt + 1, kt0 + CHUNK);

    int tid = threadIdx.x;
    int w = tid >> 6, lane = tid & 63;
    int quad = lane >> 4, l16 = lane & 15;
    int qbase = qt * 64;

    // Q fragments straight from global into registers
    bf16x8 qf[6];
    {
        int qrow = qbase + w * 16 + l16;
        #pragma unroll
        for (int kk = 0; kk < 4; ++kk)
            qf[kk] = *(const bf16x8*)&QN[(size_t)qrow * (NH * NOPE) + h * NOPE + kk * 32 + quad * 8];
        #pragma unroll
        for (int kk = 4; kk < 6; ++kk)
            qf[kk] = *(const bf16x8*)&QR[(size_t)qrow * (NH * ROPE) + h * ROPE + (kk - 4) * 32 + quad * 8];
    }

    // loop-invariant staging descriptors.
    // K tile: 64 rows x 192 bf16 = 1536 16B-chunks -> 6 per thread.
    const bf16_t* ksrc[6];
    int kofs[6], kstep[6];
    #pragma unroll
    for (int l = 0; l < 6; ++l) {
        int cid = tid + l * 256;
        int row = cid / 24, ch = cid % 24;
        kofs[l] = row * KS_STRIDE + ch * 8;
        if (ch < 16) {
            ksrc[l]  = KVU + (size_t)(kt0 * 64 + row) * (NH * 256) + h * 256 + ch * 8;
            kstep[l] = 64 * NH * 256;
        } else {
            ksrc[l]  = KR + (size_t)(kt0 * 64 + row) * ROPE + (ch - 16) * 8;
            kstep[l] = 64 * ROPE;
        }
    }
    // V tile: 128 d-rows x 64 keys = 1024 16B-chunks -> 4 per thread (coalesced from Vt).
    const bf16_t* vsrc[4];
    int vofs[4];
    #pragma unroll
    for (int l = 0; l < 4; ++l) {
        int cid = tid + l * 256;
        int vd = cid >> 3, vch = cid & 7;
        vofs[l] = vd * VS_STRIDE + vch * 8;
        vsrc[l] = Vt + ((size_t)h * VDIM + vd) * T_SEQ + kt0 * 64 + vch * 8;
    }

    bf16x8 ones;
    #pragma unroll
    for (int i = 0; i < 8; ++i) ones[i] = (bf16_t)1.0f;

    f32x4 o[8];
    #pragma unroll
    for (int nt = 0; nt < 8; ++nt) o[nt] = (f32x4){0.f, 0.f, 0.f, 0.f};
    f32x4 lacc = (f32x4){0.f, 0.f, 0.f, 0.f};

    // prologue: issue loads for tile kt0
    uint4 kreg[6], vreg[4];
    #pragma unroll
    for (int l = 0; l < 6; ++l) { kreg[l] = *(const uint4*)ksrc[l]; ksrc[l] += kstep[l]; }
    #pragma unroll
    for (int l = 0; l < 4; ++l) { vreg[l] = *(const uint4*)vsrc[l]; vsrc[l] += 64; }

    for (int kt = kt0; kt < kt1; ++kt) {
        int kbase = kt * 64;
        __syncthreads();   // all waves done reading LDS from previous tile
        #pragma unroll
        for (int l = 0; l < 6; ++l) *(uint4*)&Ks[kofs[l]] = kreg[l];
        #pragma unroll
        for (int l = 0; l < 4; ++l) *(uint4*)&Vs[vofs[l]] = vreg[l];
        __syncthreads();   // tile visible to all waves

        // issue next tile's loads; latency hides under the compute below
        if (kt + 1 < kt1) {
            #pragma unroll
            for (int l = 0; l < 6; ++l) { kreg[l] = *(const uint4*)ksrc[l]; ksrc[l] += kstep[l]; }
            #pragma unroll
            for (int l = 0; l < 4; ++l) { vreg[l] = *(const uint4*)vsrc[l]; vsrc[l] += 64; }
        }

        // S = Q K^T : 4 col-tiles x 6 k-steps
        f32x4 S[4];
        #pragma unroll
        for (int c = 0; c < 4; ++c) S[c] = (f32x4){0.f, 0.f, 0.f, 0.f};
        #pragma unroll
        for (int kk = 0; kk < 6; ++kk) {
            #pragma unroll
            for (int c = 0; c < 4; ++c) {
                bf16x8 kf = *(const bf16x8*)&Ks[(c * 16 + l16) * KS_STRIDE + kk * 32 + quad * 8];
                S[c] = __builtin_amdgcn_mfma_f32_16x16x32_bf16(qf[kk], kf, S[c], 0, 0, 0);
            }
        }

        // fixed-max softmax: p = exp(s*SCALE) (bounded; shift-invariance -> additive splits)
        #pragma unroll
        for (int c = 0; c < 4; ++c) {
            #pragma unroll
            for (int j = 0; j < 4; ++j) {
                int col = kbase + c * 16 + l16;
                int grow = qbase + w * 16 + quad * 4 + j;
                float p = (col <= grow) ? __expf(S[c][j] * SCALE) : 0.f;
                Ps[w][(quad * 4 + j) * P_STRIDE + c * 16 + l16] = (bf16_t)p;
            }
        }
        __asm__ volatile("s_waitcnt lgkmcnt(0)" ::: "memory");

        bf16x8 pf0 = *(const bf16x8*)&Ps[w][l16 * P_STRIDE + quad * 8];
        bf16x8 pf1 = *(const bf16x8*)&Ps[w][l16 * P_STRIDE + 32 + quad * 8];
        lacc = __builtin_amdgcn_mfma_f32_16x16x32_bf16(pf0, ones, lacc, 0, 0, 0);
        lacc = __builtin_amdgcn_mfma_f32_16x16x32_bf16(pf1, ones, lacc, 0, 0, 0);

        // O += P V : V fragments from LDS
        #pragma unroll
        for (int kk2 = 0; kk2 < 2; ++kk2) {
            bf16x8 pf = kk2 ? pf1 : pf0;
            #pragma unroll
            for (int nt = 0; nt < 8; ++nt) {
                bf16x8 vf = *(const bf16x8*)&Vs[(nt * 16 + l16) * VS_STRIDE + kk2 * 32 + quad * 8];
                o[nt] = __builtin_amdgcn_mfma_f32_16x16x32_bf16(pf, vf, o[nt], 0, 0, 0);
            }
        }
    }

    // write raw partials (no normalization)
    #pragma unroll
    for (int nt = 0; nt < 8; ++nt)
        #pragma unroll
        for (int j = 0; j < 4; ++j)
            Opart[(size_t)slot * 8192 + (w * 16 + quad * 4 + j) * 128 + nt * 16 + l16] = (bf16_t)o[nt][j];
    if (l16 == 0) {
        #pragma unroll
        for (int j = 0; j < 4; ++j)
            lpart[slot * 64 + w * 16 + quad * 4 + j] = lacc[j];
    }
}

// ---------------- combine: sum partials, normalize, write ao ----------------
__global__ __launch_bounds__(256) void attn_combine(
    const bf16_t* __restrict__ Opart, const float* __restrict__ lpart,
    bf16_t* __restrict__ AO)
{
    int qt = blockIdx.x, h = blockIdx.y;
    int nch = qt / CHUNK + 1;
    int base = slot_base(qt, h);
    int r = threadIdx.x >> 2, c0 = (threadIdx.x & 3) * 32;

    float acc[32];
    #pragma unroll
    for (int i = 0; i < 32; ++i) acc[i] = 0.f;
    float lsum = 0.f;
    for (int ch = 0; ch < nch; ++ch) {
        int slot = base + ch;
        const bf16_t* p = &Opart[(size_t)slot * 8192 + r * 128 + c0];
        #pragma unroll
        for (int v = 0; v < 4; ++v) {
            bf16x8 u = *(const bf16x8*)&p[v * 8];
            #pragma unroll
            for (int e = 0; e < 8; ++e) acc[v * 8 + e] += (float)u[e];
        }
        lsum += lpart[slot * 64 + r];
    }
    float inv = 1.0f / lsum;
    bf16_t* dst = AO + (size_t)(qt * 64 + r) * (NH * VDIM) + h * VDIM + c0;
    #pragma unroll
    for (int v = 0; v < 4; ++v) {
        bf16_t tmp[8];
        #pragma unroll
        for (int e = 0; e < 8; ++e) tmp[e] = (bf16_t)(acc[v * 8 + e] * inv);
        *(uint4*)&dst[v * 8] = *(const uint4*)tmp;
    }
}

// ---------------- launch ----------------
extern "C" void kernel_launch(void* const* d_in, const int* in_sizes, int n_in,
                              void* d_out, int out_size, void* d_ws, size_t ws_size,
                              hipStream_t stream) {
    const float* x        = (const float*)d_in[0];
    const float* freqs    = (const float*)d_in[1];
    // d_in[2] = mask (unused; causality applied analytically)
    const float* wq_down  = (const float*)d_in[3];
    const float* q_norm_w = (const float*)d_in[4];
    const float* wq_nope  = (const float*)d_in[5];
    const float* wq_rope  = (const float*)d_in[6];
    const float* wkv_down = (const float*)d_in[7];
    const float* kv_norm_w= (const float*)d_in[8];
    const float* wkv_up   = (const float*)d_in[9];
    const float* wo       = (const float*)d_in[10];
    float* out = (float*)d_out;

    bf16_t* ws = (bf16_t*)d_ws;
    // ---- pool region (two time-disjoint views), 25,493,504 bf16 elems ----
    // A-view: pre-attention transients
    bf16_t* xb     = ws;                     // 3072*2048
    bf16_t* wqd_t  = xb     + 6291456;       // [1536][2048]
    bf16_t* wkvd_t = wqd_t  + 3145728;       // [576][2048]
    bf16_t* wqn_t  = wkvd_t + 1179648;       // [2048][1536]
    bf16_t* wqr_t  = wqn_t  + 3145728;       // [1024][1536]
    bf16_t* wkvu_t = wqr_t  + 1572864;       // [4096][512]
    bf16_t* t1     = wkvu_t + 2097152;       // 3072*1536 (q_lat)
    bf16_t* kvd    = t1     + 4718592;       // 3072*576
    bf16_t* ckvn   = kvd    + 1769472;       // 3072*512  (ends at 25,493,504)
    // B-view: attention partials + ao
    bf16_t* Opart  = ws;                     // 1920 slots * 8192
    float*  lpart  = (float*)(ws + 15728640);// 1920 * 64 fp32
    bf16_t* ao     = ws + 15728640 + 245760; // 3072*2048
    // ---- tail region (long-lived) ----
    bf16_t* wo_t   = ws    + 25493504;       // [2048][2048]
    bf16_t* kr     = wo_t  + 4194304;        // 3072*64
    bf16_t* qn     = kr    + 196608;         // 3072*2048
    bf16_t* qr     = qn    + 6291456;        // 3072*1024
    bf16_t* kvu    = qr    + 3145728;        // 3072*4096
    bf16_t* vt     = kvu   + 12582912;       // [16][128][3072]  (total 58,195,968)

    // converts + weight transposes
    f2b_kernel<<<T_SEQ * DIM / 4 / 256, 256, 0, stream>>>(x, xb, T_SEQ * DIM);
    transp_kernel<<<dim3(QLORA / 32, DIM / 32), 256, 0, stream>>>(wq_down, wqd_t, DIM, QLORA);
    transp_kernel<<<dim3((KVLORA + ROPE) / 32, DIM / 32), 256, 0, stream>>>(wkv_down, wkvd_t, DIM, KVLORA + ROPE);
    transp_kernel<<<dim3(NH * NOPE / 32, QLORA / 32), 256, 0, stream>>>(wq_nope, wqn_t, QLORA, NH * NOPE);
    transp_kernel<<<dim3(NH * ROPE / 32, QLORA / 32), 256, 0, stream>>>(wq_rope, wqr_t, QLORA, NH * ROPE);
    transp_kernel<<<dim3(NH * 256 / 32, KVLORA / 32), 256, 0, stream>>>(wkv_up, wkvu_t, KVLORA, NH * 256);
    transp_kernel<<<dim3(DIM / 32, DIM / 32), 256, 0, stream>>>(wo, wo_t, DIM, DIM);

    // down-projections
    gemm_mfma<<<dim3(QLORA / 128, T_SEQ / 128), 256, 0, stream>>>(xb, wqd_t, nullptr, t1, T_SEQ, QLORA, DIM, 0);
    gemm_mfma<<<dim3(5, T_SEQ / 128), 256, 0, stream>>>(xb, wkvd_t, nullptr, kvd, T_SEQ, KVLORA + ROPE, DIM, 0);

    rmsnorm_rows<<<T_SEQ, 256, 0, stream>>>(t1, q_norm_w, QLORA);
    kv_post<<<T_SEQ, 256, 0, stream>>>(kvd, kv_norm_w, freqs, ckvn, kr);

    // up-projections
    gemm_mfma<<<dim3(NH * NOPE / 128, T_SEQ / 128), 256, 0, stream>>>(t1, wqn_t, nullptr, qn, T_SEQ, NH * NOPE, QLORA, 0);
    gemm_mfma<<<dim3(NH * ROPE / 128, T_SEQ / 128), 256, 0, stream>>>(t1, wqr_t, nullptr, qr, T_SEQ, NH * ROPE, QLORA, 0);
    rope_q<<<(T_SEQ * NH * 32 + 255) / 256, 256, 0, stream>>>(qr, freqs);
    gemm_mfma<<<dim3(NH * 256 / 128, T_SEQ / 128), 256, 0, stream>>>(ckvn, wkvu_t, nullptr, kvu, T_SEQ, NH * 256, KVLORA, 0);

    // V transpose for attention B-operand
    vt_transp<<<dim3(T_SEQ / 32, VDIM / 32, NH), 256, 0, stream>>>(kvu, vt);

    // split-K attention + combine
    attn_v6<<<dim3(T_SEQ / 64, 4, NH), 256, 0, stream>>>(qn, qr, kvu, kr, vt, Opart, lpart);
    attn_combine<<<dim3(T_SEQ / 64, NH), 256, 0, stream>>>(Opart, lpart, ao);

    // output projection (fp32 out)
    gemm_mfma<<<dim3(DIM / 128, T_SEQ / 128), 256, 0, stream>>>(ao, wo_t, out, nullptr, T_SEQ, DIM, DIM, 1);
}

// Round 3
// 811.408 us; speedup vs baseline: 1.0000x; 1.0000x over previous
//
#include <hip/hip_runtime.h>
#include <hip/hip_bf16.h>

typedef __bf16 bf16_t;
typedef __bf16 bf16x8 __attribute__((ext_vector_type(8)));
typedef float f32x4 __attribute__((ext_vector_type(4)));

// Problem constants
#define T_SEQ 3072
#define DIM 2048
#define NH 16
#define QLORA 1536
#define KVLORA 512
#define NOPE 128
#define ROPE 64
#define VDIM 128
#define HD 192          // NOPE+ROPE
#define SCALE 0.07216878364870323f  // 192^-0.5
#define CHUNK 12        // k-tiles (of 64 keys) per attention block

// ---------------- helpers ----------------
__device__ inline float wave_reduce_sum(float v) {
    #pragma unroll
    for (int off = 32; off > 0; off >>= 1) v += __shfl_down(v, off);
    return v;
}

__device__ inline float block_reduce_sum_256(float v) {
    __shared__ float red[4];
    int lane = threadIdx.x & 63, w = threadIdx.x >> 6;
    v = wave_reduce_sum(v);
    if (lane == 0) red[w] = v;
    __syncthreads();
    if (threadIdx.x == 0) red[0] = red[0] + red[1] + red[2] + red[3];
    __syncthreads();
    return red[0];
}

// async global->LDS, 16B per lane. LDS dest must be linear: wave-uniform base + lane*16.
__device__ inline void glds16(const bf16_t* g, bf16_t* l) {
    __builtin_amdgcn_global_load_lds(
        (const __attribute__((address_space(1))) unsigned int*)g,
        (__attribute__((address_space(3))) unsigned int*)l, 16, 0, 0);
}

// ---------------- fp32 -> bf16 convert ----------------
__global__ void f2b_kernel(const float* __restrict__ in, bf16_t* __restrict__ out, int n) {
    int i = (blockIdx.x * 256 + threadIdx.x) * 4;
    if (i < n) {
        float4 v = *(const float4*)&in[i];
        bf16_t o[4] = {(bf16_t)v.x, (bf16_t)v.y, (bf16_t)v.z, (bf16_t)v.w};
        *(uint2*)&out[i] = *(const uint2*)o;
    }
}

// ---------------- fp32 [K][N] -> bf16 [N][K] transpose-convert ----------------
__global__ __launch_bounds__(256) void transp_kernel(
    const float* __restrict__ in, bf16_t* __restrict__ out, int K, int N)
{
    __shared__ float tile[32][33];
    int k0 = blockIdx.y * 32, n0 = blockIdx.x * 32;
    int tx = threadIdx.x & 31, ty = threadIdx.x >> 5;
    #pragma unroll
    for (int i = 0; i < 4; ++i)
        tile[ty + i * 8][tx] = in[(size_t)(k0 + ty + i * 8) * N + n0 + tx];
    __syncthreads();
    #pragma unroll
    for (int i = 0; i < 4; ++i)
        out[(size_t)(n0 + ty + i * 8) * K + k0 + tx] = (bf16_t)tile[tx][ty + i * 8];
}

// ---------------- bf16 kvu V-part -> vt[h][d][t] transpose ----------------
__global__ __launch_bounds__(256) void vt_transp(
    const bf16_t* __restrict__ kvu, bf16_t* __restrict__ vt)
{
    __shared__ bf16_t tile[32][34];
    int t0 = blockIdx.x * 32, d0 = blockIdx.y * 32, h = blockIdx.z;
    int tx = threadIdx.x & 31, ty = threadIdx.x >> 5;
    #pragma unroll
    for (int i = 0; i < 4; ++i)
        tile[ty + i * 8][tx] = kvu[(size_t)(t0 + ty + i * 8) * (NH * 256) + h * 256 + NOPE + d0 + tx];
    __syncthreads();
    #pragma unroll
    for (int i = 0; i < 4; ++i)
        vt[((size_t)h * VDIM + d0 + ty + i * 8) * T_SEQ + t0 + tx] = tile[tx][ty + i * 8];
}

// ---------------- MFMA GEMM (m97 structure): C[M,N] = A[M,K](bf16) x Bt[N,K](bf16) ----------------
// 128x128 tile, BK=32, linear LDS staged via global_load_lds width=16.
__global__ __launch_bounds__(256) void gemm_mfma(
    const bf16_t* __restrict__ A, const bf16_t* __restrict__ Bt,
    float* __restrict__ Cf, bf16_t* __restrict__ Cb,
    int M, int N, int K, int writef)
{
    __shared__ __align__(16) bf16_t As[128 * 32];
    __shared__ __align__(16) bf16_t Bs[128 * 32];
    int tid = threadIdx.x;
    int w = tid >> 6, lane = tid & 63;
    int quad = lane >> 4, l16 = lane & 15;
    int bm = blockIdx.y * 128, bn = blockIdx.x * 128;
    int wm = (w & 1) * 64, wn = (w >> 1) * 64;

    // staging coords: thread stages rows srow and srow+64, 16B chunk soff
    int srow = tid >> 2, soff = (tid & 3) * 8;
    const bf16_t* a0 = A + (size_t)(bm + srow) * K + soff;
    const bf16_t* a1 = A + (size_t)(bm + 64 + srow) * K + soff;
    int br0 = bn + srow;      if (br0 >= N) br0 = N - 1;   // clamp (cols >= N never written)
    int br1 = bn + 64 + srow; if (br1 >= N) br1 = N - 1;
    const bf16_t* b0 = Bt + (size_t)br0 * K + soff;
    const bf16_t* b1 = Bt + (size_t)br1 * K + soff;
    bf16_t* la = &As[tid * 8];   // byte off = tid*16 = wave_base + lane*16
    bf16_t* lb = &Bs[tid * 8];

    f32x4 acc[4][4];
    #pragma unroll
    for (int i = 0; i < 4; ++i)
        #pragma unroll
        for (int j = 0; j < 4; ++j)
            acc[i][j] = (f32x4){0.f, 0.f, 0.f, 0.f};

    for (int k0 = 0; k0 < K; k0 += 32) {
        glds16(a0 + k0, la);
        glds16(a1 + k0, la + 2048);
        glds16(b0 + k0, lb);
        glds16(b1 + k0, lb + 2048);
        __syncthreads();   // compiler drains vmcnt before s_barrier
        bf16x8 af[4], bfr[4];
        #pragma unroll
        for (int t = 0; t < 4; ++t) {
            af[t]  = *(const bf16x8*)&As[(wm + t * 16 + l16) * 32 + quad * 8];
            bfr[t] = *(const bf16x8*)&Bs[(wn + t * 16 + l16) * 32 + quad * 8];
        }
        #pragma unroll
        for (int i = 0; i < 4; ++i)
            #pragma unroll
            for (int j = 0; j < 4; ++j)
                acc[i][j] = __builtin_amdgcn_mfma_f32_16x16x32_bf16(af[i], bfr[j], acc[i][j], 0, 0, 0);
        __syncthreads();
    }

    #pragma unroll
    for (int i = 0; i < 4; ++i) {
        #pragma unroll
        for (int j = 0; j < 4; ++j) {
            #pragma unroll
            for (int r = 0; r < 4; ++r) {
                int row = bm + wm + i * 16 + quad * 4 + r;
                int col = bn + wn + j * 16 + l16;
                if (col < N) {
                    if (writef) Cf[(size_t)row * N + col] = acc[i][j][r];
                    else        Cb[(size_t)row * N + col] = (bf16_t)acc[i][j][r];
                }
            }
        }
    }
}

// ---------------- rmsnorm in-place over rows ----------------
__global__ __launch_bounds__(256) void rmsnorm_rows(
    bf16_t* __restrict__ X, const float* __restrict__ w, int N)
{
    int row = blockIdx.x;
    bf16_t* x = X + (size_t)row * N;
    float ss = 0.f;
    for (int i = threadIdx.x; i < N; i += 256) { float v = (float)x[i]; ss += v * v; }
    ss = block_reduce_sum_256(ss);
    float sc = rsqrtf(ss / (float)N + 1e-6f);
    for (int i = threadIdx.x; i < N; i += 256)
        x[i] = (bf16_t)((float)x[i] * sc * w[i]);
}

// ---------------- kv post ----------------
__global__ __launch_bounds__(256) void kv_post(
    const bf16_t* __restrict__ kvd, const float* __restrict__ w,
    const float* __restrict__ freqs,
    bf16_t* __restrict__ ckvn, bf16_t* __restrict__ kr)
{
    int row = blockIdx.x;
    const bf16_t* src = kvd + (size_t)row * (KVLORA + ROPE);
    float ss = 0.f;
    for (int i = threadIdx.x; i < KVLORA; i += 256) { float v = (float)src[i]; ss += v * v; }
    ss = block_reduce_sum_256(ss);
    float sc = rsqrtf(ss / (float)KVLORA + 1e-6f);
    for (int i = threadIdx.x; i < KVLORA; i += 256)
        ckvn[(size_t)row * KVLORA + i] = (bf16_t)((float)src[i] * sc * w[i]);
    if (threadIdx.x < 32) {
        int i = threadIdx.x;
        float f = freqs[row * 32 + i];
        float c = cosf(f), s = sinf(f);
        float x1 = (float)src[KVLORA + 2 * i], x2 = (float)src[KVLORA + 2 * i + 1];
        kr[(size_t)row * ROPE + 2 * i]     = (bf16_t)(x1 * c - x2 * s);
        kr[(size_t)row * ROPE + 2 * i + 1] = (bf16_t)(x1 * s + x2 * c);
    }
}

// ---------------- rope on q_rope in-place ----------------
__global__ void rope_q(bf16_t* __restrict__ qr, const float* __restrict__ freqs) {
    int idx = blockIdx.x * 256 + threadIdx.x;
    if (idx >= T_SEQ * NH * 32) return;
    int t = idx >> 9;
    int rem = idx & 511;
    int h = rem >> 5;
    int i = rem & 31;
    float f = freqs[t * 32 + i];
    float c = cosf(f), s = sinf(f);
    bf16_t* p = qr + (size_t)t * (NH * ROPE) + h * ROPE + 2 * i;
    float x1 = (float)p[0], x2 = (float)p[1];
    p[0] = (bf16_t)(x1 * c - x2 * s);
    p[1] = (bf16_t)(x1 * s + x2 * c);
}

// ---------------- split-K MFMA flash attention (causal, fixed-max softmax) ----------------
// v7: identical structure to v6 (LDS-staged K+V, reg-prefetch double buffering).
// launch_bounds (256, 1): min-waves/EU=1 grants the allocator the full 512-VGPR
// budget. v5's (256,3) capped at 80 VGPR and v6's bare (256) let the backend pick
// a ~5-wave occupancy target (92 VGPR); both spilled ~600-700 MB of scratch
// (WRITE_SIZE counter) for a kernel that needs ~190 live regs. LDS (53KB) limits
// residency to <=3 blocks/CU anyway, so the extra-occupancy cap bought nothing.
#define KS_STRIDE 200   // 192+8 bf16
#define VS_STRIDE 72    // 64+8 bf16
#define P_STRIDE 72     // 64+8 bf16
__device__ inline int slot_base(int qt, int h) {
    int b = qt / CHUNK;
    return h * 120 + qt + 6 * b * (b - 1) + (qt - CHUNK * b) * b;
}
__global__ __launch_bounds__(256, 1) void attn_v7(
    const bf16_t* __restrict__ QN, const bf16_t* __restrict__ QR,
    const bf16_t* __restrict__ KVU, const bf16_t* __restrict__ KR,
    const bf16_t* __restrict__ Vt,
    bf16_t* __restrict__ Opart, float* __restrict__ lpart)
{
    __shared__ __align__(16) bf16_t Ks[64 * KS_STRIDE];   // 25600 B
    __shared__ __align__(16) bf16_t Vs[128 * VS_STRIDE];  // 18432 B
    __shared__ __align__(16) bf16_t Ps[4][16 * P_STRIDE]; //  9216 B

    int qt = blockIdx.x, cx = blockIdx.y, h = blockIdx.z;
    if (cx > qt / CHUNK) return;
    int slot = slot_base(qt, h) + cx;
    int kt0 = cx * CHUNK;
    int kt1 = min(qt + 1, kt0 + CHUNK);

    int tid = threadIdx.x;
    int w = tid >> 6, lane = tid & 63;
    int quad = lane >> 4, l16 = lane & 15;
    int qbase = qt * 64;

    // Q fragments straight from global into registers
    bf16x8 qf[6];
    {
        int qrow = qbase + w * 16 + l16;
        #pragma unroll
        for (int kk = 0; kk < 4; ++kk)
            qf[kk] = *(const bf16x8*)&QN[(size_t)qrow * (NH * NOPE) + h * NOPE + kk * 32 + quad * 8];
        #pragma unroll
        for (int kk = 4; kk < 6; ++kk)
            qf[kk] = *(const bf16x8*)&QR[(size_t)qrow * (NH * ROPE) + h * ROPE + (kk - 4) * 32 + quad * 8];
    }

    // loop-invariant staging descriptors.
    // K tile: 64 rows x 192 bf16 = 1536 16B-chunks -> 6 per thread.
    const bf16_t* ksrc[6];
    int kofs[6], kstep[6];
    #pragma unroll
    for (int l = 0; l < 6; ++l) {
        int cid = tid + l * 256;
        int row = cid / 24, ch = cid % 24;
        kofs[l] = row * KS_STRIDE + ch * 8;
        if (ch < 16) {
            ksrc[l]  = KVU + (size_t)(kt0 * 64 + row) * (NH * 256) + h * 256 + ch * 8;
            kstep[l] = 64 * NH * 256;
        } else {
            ksrc[l]  = KR + (size_t)(kt0 * 64 + row) * ROPE + (ch - 16) * 8;
            kstep[l] = 64 * ROPE;
        }
    }
    // V tile: 128 d-rows x 64 keys = 1024 16B-chunks -> 4 per thread (coalesced from Vt).
    const bf16_t* vsrc[4];
    int vofs[4];
    #pragma unroll
    for (int l = 0; l < 4; ++l) {
        int cid = tid + l * 256;
        int vd = cid >> 3, vch = cid & 7;
        vofs[l] = vd * VS_STRIDE + vch * 8;
        vsrc[l] = Vt + ((size_t)h * VDIM + vd) * T_SEQ + kt0 * 64 + vch * 8;
    }

    bf16x8 ones;
    #pragma unroll
    for (int i = 0; i < 8; ++i) ones[i] = (bf16_t)1.0f;

    f32x4 o[8];
    #pragma unroll
    for (int nt = 0; nt < 8; ++nt) o[nt] = (f32x4){0.f, 0.f, 0.f, 0.f};
    f32x4 lacc = (f32x4){0.f, 0.f, 0.f, 0.f};

    // prologue: issue loads for tile kt0
    uint4 kreg[6], vreg[4];
    #pragma unroll
    for (int l = 0; l < 6; ++l) { kreg[l] = *(const uint4*)ksrc[l]; ksrc[l] += kstep[l]; }
    #pragma unroll
    for (int l = 0; l < 4; ++l) { vreg[l] = *(const uint4*)vsrc[l]; vsrc[l] += 64; }

    for (int kt = kt0; kt < kt1; ++kt) {
        int kbase = kt * 64;
        __syncthreads();   // all waves done reading LDS from previous tile
        #pragma unroll
        for (int l = 0; l < 6; ++l) *(uint4*)&Ks[kofs[l]] = kreg[l];
        #pragma unroll
        for (int l = 0; l < 4; ++l) *(uint4*)&Vs[vofs[l]] = vreg[l];
        __syncthreads();   // tile visible to all waves

        // issue next tile's loads; latency hides under the compute below
        if (kt + 1 < kt1) {
            #pragma unroll
            for (int l = 0; l < 6; ++l) { kreg[l] = *(const uint4*)ksrc[l]; ksrc[l] += kstep[l]; }
            #pragma unroll
            for (int l = 0; l < 4; ++l) { vreg[l] = *(const uint4*)vsrc[l]; vsrc[l] += 64; }
        }

        // S = Q K^T : 4 col-tiles x 6 k-steps
        f32x4 S[4];
        #pragma unroll
        for (int c = 0; c < 4; ++c) S[c] = (f32x4){0.f, 0.f, 0.f, 0.f};
        #pragma unroll
        for (int kk = 0; kk < 6; ++kk) {
            #pragma unroll
            for (int c = 0; c < 4; ++c) {
                bf16x8 kf = *(const bf16x8*)&Ks[(c * 16 + l16) * KS_STRIDE + kk * 32 + quad * 8];
                S[c] = __builtin_amdgcn_mfma_f32_16x16x32_bf16(qf[kk], kf, S[c], 0, 0, 0);
            }
        }

        // fixed-max softmax: p = exp(s*SCALE) (bounded; shift-invariance -> additive splits)
        #pragma unroll
        for (int c = 0; c < 4; ++c) {
            #pragma unroll
            for (int j = 0; j < 4; ++j) {
                int col = kbase + c * 16 + l16;
                int grow = qbase + w * 16 + quad * 4 + j;
                float p = (col <= grow) ? __expf(S[c][j] * SCALE) : 0.f;
                Ps[w][(quad * 4 + j) * P_STRIDE + c * 16 + l16] = (bf16_t)p;
            }
        }
        __asm__ volatile("s_waitcnt lgkmcnt(0)" ::: "memory");

        bf16x8 pf0 = *(const bf16x8*)&Ps[w][l16 * P_STRIDE + quad * 8];
        bf16x8 pf1 = *(const bf16x8*)&Ps[w][l16 * P_STRIDE + 32 + quad * 8];
        lacc = __builtin_amdgcn_mfma_f32_16x16x32_bf16(pf0, ones, lacc, 0, 0, 0);
        lacc = __builtin_amdgcn_mfma_f32_16x16x32_bf16(pf1, ones, lacc, 0, 0, 0);

        // O += P V : V fragments from LDS
        #pragma unroll
        for (int kk2 = 0; kk2 < 2; ++kk2) {
            bf16x8 pf = kk2 ? pf1 : pf0;
            #pragma unroll
            for (int nt = 0; nt < 8; ++nt) {
                bf16x8 vf = *(const bf16x8*)&Vs[(nt * 16 + l16) * VS_STRIDE + kk2 * 32 + quad * 8];
                o[nt] = __builtin_amdgcn_mfma_f32_16x16x32_bf16(pf, vf, o[nt], 0, 0, 0);
            }
        }
    }

    // write raw partials (no normalization)
    #pragma unroll
    for (int nt = 0; nt < 8; ++nt)
        #pragma unroll
        for (int j = 0; j < 4; ++j)
            Opart[(size_t)slot * 8192 + (w * 16 + quad * 4 + j) * 128 + nt * 16 + l16] = (bf16_t)o[nt][j];
    if (l16 == 0) {
        #pragma unroll
        for (int j = 0; j < 4; ++j)
            lpart[slot * 64 + w * 16 + quad * 4 + j] = lacc[j];
    }
}

// ---------------- combine: sum partials, normalize, write ao ----------------
__global__ __launch_bounds__(256) void attn_combine(
    const bf16_t* __restrict__ Opart, const float* __restrict__ lpart,
    bf16_t* __restrict__ AO)
{
    int qt = blockIdx.x, h = blockIdx.y;
    int nch = qt / CHUNK + 1;
    int base = slot_base(qt, h);
    int r = threadIdx.x >> 2, c0 = (threadIdx.x & 3) * 32;

    float acc[32];
    #pragma unroll
    for (int i = 0; i < 32; ++i) acc[i] = 0.f;
    float lsum = 0.f;
    for (int ch = 0; ch < nch; ++ch) {
        int slot = base + ch;
        const bf16_t* p = &Opart[(size_t)slot * 8192 + r * 128 + c0];
        #pragma unroll
        for (int v = 0; v < 4; ++v) {
            bf16x8 u = *(const bf16x8*)&p[v * 8];
            #pragma unroll
            for (int e = 0; e < 8; ++e) acc[v * 8 + e] += (float)u[e];
        }
        lsum += lpart[slot * 64 + r];
    }
    float inv = 1.0f / lsum;
    bf16_t* dst = AO + (size_t)(qt * 64 + r) * (NH * VDIM) + h * VDIM + c0;
    #pragma unroll
    for (int v = 0; v < 4; ++v) {
        bf16_t tmp[8];
        #pragma unroll
        for (int e = 0; e < 8; ++e) tmp[e] = (bf16_t)(acc[v * 8 + e] * inv);
        *(uint4*)&dst[v * 8] = *(const uint4*)tmp;
    }
}

// ---------------- launch ----------------
extern "C" void kernel_launch(void* const* d_in, const int* in_sizes, int n_in,
                              void* d_out, int out_size, void* d_ws, size_t ws_size,
                              hipStream_t stream) {
    const float* x        = (const float*)d_in[0];
    const float* freqs    = (const float*)d_in[1];
    // d_in[2] = mask (unused; causality applied analytically)
    const float* wq_down  = (const float*)d_in[3];
    const float* q_norm_w = (const float*)d_in[4];
    const float* wq_nope  = (const float*)d_in[5];
    const float* wq_rope  = (const float*)d_in[6];
    const float* wkv_down = (const float*)d_in[7];
    const float* kv_norm_w= (const float*)d_in[8];
    const float* wkv_up   = (const float*)d_in[9];
    const float* wo       = (const float*)d_in[10];
    float* out = (float*)d_out;

    bf16_t* ws = (bf16_t*)d_ws;
    // ---- pool region (two time-disjoint views), 25,493,504 bf16 elems ----
    // A-view: pre-attention transients
    bf16_t* xb     = ws;                     // 3072*2048
    bf16_t* wqd_t  = xb     + 6291456;       // [1536][2048]
    bf16_t* wkvd_t = wqd_t  + 3145728;       // [576][2048]
    bf16_t* wqn_t  = wkvd_t + 1179648;       // [2048][1536]
    bf16_t* wqr_t  = wqn_t  + 3145728;       // [1024][1536]
    bf16_t* wkvu_t = wqr_t  + 1572864;       // [4096][512]
    bf16_t* t1     = wkvu_t + 2097152;       // 3072*1536 (q_lat)
    bf16_t* kvd    = t1     + 4718592;       // 3072*576
    bf16_t* ckvn   = kvd    + 1769472;       // 3072*512  (ends at 25,493,504)
    // B-view: attention partials + ao
    bf16_t* Opart  = ws;                     // 1920 slots * 8192
    float*  lpart  = (float*)(ws + 15728640);// 1920 * 64 fp32
    bf16_t* ao     = ws + 15728640 + 245760; // 3072*2048
    // ---- tail region (long-lived) ----
    bf16_t* wo_t   = ws    + 25493504;       // [2048][2048]
    bf16_t* kr     = wo_t  + 4194304;        // 3072*64
    bf16_t* qn     = kr    + 196608;         // 3072*2048
    bf16_t* qr     = qn    + 6291456;        // 3072*1024
    bf16_t* kvu    = qr    + 3145728;        // 3072*4096
    bf16_t* vt     = kvu   + 12582912;       // [16][128][3072]  (total 58,195,968)

    // converts + weight transposes
    f2b_kernel<<<T_SEQ * DIM / 4 / 256, 256, 0, stream>>>(x, xb, T_SEQ * DIM);
    transp_kernel<<<dim3(QLORA / 32, DIM / 32), 256, 0, stream>>>(wq_down, wqd_t, DIM, QLORA);
    transp_kernel<<<dim3((KVLORA + ROPE) / 32, DIM / 32), 256, 0, stream>>>(wkv_down, wkvd_t, DIM, KVLORA + ROPE);
    transp_kernel<<<dim3(NH * NOPE / 32, QLORA / 32), 256, 0, stream>>>(wq_nope, wqn_t, QLORA, NH * NOPE);
    transp_kernel<<<dim3(NH * ROPE / 32, QLORA / 32), 256, 0, stream>>>(wq_rope, wqr_t, QLORA, NH * ROPE);
    transp_kernel<<<dim3(NH * 256 / 32, KVLORA / 32), 256, 0, stream>>>(wkv_up, wkvu_t, KVLORA, NH * 256);
    transp_kernel<<<dim3(DIM / 32, DIM / 32), 256, 0, stream>>>(wo, wo_t, DIM, DIM);

    // down-projections
    gemm_mfma<<<dim3(QLORA / 128, T_SEQ / 128), 256, 0, stream>>>(xb, wqd_t, nullptr, t1, T_SEQ, QLORA, DIM, 0);
    gemm_mfma<<<dim3(5, T_SEQ / 128), 256, 0, stream>>>(xb, wkvd_t, nullptr, kvd, T_SEQ, KVLORA + ROPE, DIM, 0);

    rmsnorm_rows<<<T_SEQ, 256, 0, stream>>>(t1, q_norm_w, QLORA);
    kv_post<<<T_SEQ, 256, 0, stream>>>(kvd, kv_norm_w, freqs, ckvn, kr);

    // up-projections
    gemm_mfma<<<dim3(NH * NOPE / 128, T_SEQ / 128), 256, 0, stream>>>(t1, wqn_t, nullptr, qn, T_SEQ, NH * NOPE, QLORA, 0);
    gemm_mfma<<<dim3(NH * ROPE / 128, T_SEQ / 128), 256, 0, stream>>>(t1, wqr_t, nullptr, qr, T_SEQ, NH * ROPE, QLORA, 0);
    rope_q<<<(T_SEQ * NH * 32 + 255) / 256, 256, 0, stream>>>(qr, freqs);
    gemm_mfma<<<dim3(NH * 256 / 128, T_SEQ / 128), 256, 0, stream>>>(ckvn, wkvu_t, nullptr, kvu, T_SEQ, NH * 256, KVLORA, 0);

    // V transpose for attention B-operand
    vt_transp<<<dim3(T_SEQ / 32, VDIM / 32, NH), 256, 0, stream>>>(kvu, vt);

    // split-K attention + combine
    attn_v7<<<dim3(T_SEQ / 64, 4, NH), 256, 0, stream>>>(qn, qr, kvu, kr, vt, Opart, lpart);
    attn_combine<<<dim3(T_SEQ / 64, NH), 256, 0, stream>>>(Opart, lpart, ao);

    // output projection (fp32 out)
    gemm_mfma<<<dim3(DIM / 128, T_SEQ / 128), 256, 0, stream>>>(ao, wo_t, out, nullptr, T_SEQ, DIM, DIM, 1);
}

// Round 4
// 572.493 us; speedup vs baseline: 1.4173x; 1.4173x over previous
//
#include <hip/hip_runtime.h>
#include <hip/hip_bf16.h>

typedef __bf16 bf16_t;
typedef __bf16 bf16x8 __attribute__((ext_vector_type(8)));
typedef float f32x4 __attribute__((ext_vector_type(4)));

// Problem constants
#define T_SEQ 3072
#define DIM 2048
#define NH 16
#define QLORA 1536
#define KVLORA 512
#define NOPE 128
#define ROPE 64
#define VDIM 128
#define HD 192          // NOPE+ROPE
#define SCALE 0.07216878364870323f  // 192^-0.5
#define CHUNK 12        // k-tiles (of 64 keys) per attention block

// ---------------- helpers ----------------
__device__ inline float wave_reduce_sum(float v) {
    #pragma unroll
    for (int off = 32; off > 0; off >>= 1) v += __shfl_down(v, off);
    return v;
}

__device__ inline float block_reduce_sum_256(float v) {
    __shared__ float red[4];
    int lane = threadIdx.x & 63, w = threadIdx.x >> 6;
    v = wave_reduce_sum(v);
    if (lane == 0) red[w] = v;
    __syncthreads();
    if (threadIdx.x == 0) red[0] = red[0] + red[1] + red[2] + red[3];
    __syncthreads();
    return red[0];
}

// async global->LDS, 16B per lane. LDS dest is wave-uniform base + lane*16 (linear).
// Global source address is per-lane (pre-swizzle it to realize swizzled LDS layouts).
__device__ inline void glds16(const bf16_t* g, bf16_t* l) {
    __builtin_amdgcn_global_load_lds(
        (const __attribute__((address_space(1))) unsigned int*)g,
        (__attribute__((address_space(3))) unsigned int*)l, 16, 0, 0);
}

// ---------------- fp32 -> bf16 convert ----------------
__global__ void f2b_kernel(const float* __restrict__ in, bf16_t* __restrict__ out, int n) {
    int i = (blockIdx.x * 256 + threadIdx.x) * 4;
    if (i < n) {
        float4 v = *(const float4*)&in[i];
        bf16_t o[4] = {(bf16_t)v.x, (bf16_t)v.y, (bf16_t)v.z, (bf16_t)v.w};
        *(uint2*)&out[i] = *(const uint2*)o;
    }
}

// ---------------- fp32 [K][N] -> bf16 [N][K] transpose-convert ----------------
__global__ __launch_bounds__(256) void transp_kernel(
    const float* __restrict__ in, bf16_t* __restrict__ out, int K, int N)
{
    __shared__ float tile[32][33];
    int k0 = blockIdx.y * 32, n0 = blockIdx.x * 32;
    int tx = threadIdx.x & 31, ty = threadIdx.x >> 5;
    #pragma unroll
    for (int i = 0; i < 4; ++i)
        tile[ty + i * 8][tx] = in[(size_t)(k0 + ty + i * 8) * N + n0 + tx];
    __syncthreads();
    #pragma unroll
    for (int i = 0; i < 4; ++i)
        out[(size_t)(n0 + ty + i * 8) * K + k0 + tx] = (bf16_t)tile[tx][ty + i * 8];
}

// ---------------- bf16 kvu V-part -> vt[h][d][t] transpose ----------------
__global__ __launch_bounds__(256) void vt_transp(
    const bf16_t* __restrict__ kvu, bf16_t* __restrict__ vt)
{
    __shared__ bf16_t tile[32][34];
    int t0 = blockIdx.x * 32, d0 = blockIdx.y * 32, h = blockIdx.z;
    int tx = threadIdx.x & 31, ty = threadIdx.x >> 5;
    #pragma unroll
    for (int i = 0; i < 4; ++i)
        tile[ty + i * 8][tx] = kvu[(size_t)(t0 + ty + i * 8) * (NH * 256) + h * 256 + NOPE + d0 + tx];
    __syncthreads();
    #pragma unroll
    for (int i = 0; i < 4; ++i)
        vt[((size_t)h * VDIM + d0 + ty + i * 8) * T_SEQ + t0 + tx] = tile[tx][ty + i * 8];
}

// ---------------- MFMA GEMM (m97 structure): C[M,N] = A[M,K](bf16) x Bt[N,K](bf16) ----------------
// 128x128 tile, BK=32, linear LDS staged via global_load_lds width=16.
__global__ __launch_bounds__(256) void gemm_mfma(
    const bf16_t* __restrict__ A, const bf16_t* __restrict__ Bt,
    float* __restrict__ Cf, bf16_t* __restrict__ Cb,
    int M, int N, int K, int writef)
{
    __shared__ __align__(16) bf16_t As[128 * 32];
    __shared__ __align__(16) bf16_t Bs[128 * 32];
    int tid = threadIdx.x;
    int w = tid >> 6, lane = tid & 63;
    int quad = lane >> 4, l16 = lane & 15;
    int bm = blockIdx.y * 128, bn = blockIdx.x * 128;
    int wm = (w & 1) * 64, wn = (w >> 1) * 64;

    // staging coords: thread stages rows srow and srow+64, 16B chunk soff
    int srow = tid >> 2, soff = (tid & 3) * 8;
    const bf16_t* a0 = A + (size_t)(bm + srow) * K + soff;
    const bf16_t* a1 = A + (size_t)(bm + 64 + srow) * K + soff;
    int br0 = bn + srow;      if (br0 >= N) br0 = N - 1;   // clamp (cols >= N never written)
    int br1 = bn + 64 + srow; if (br1 >= N) br1 = N - 1;
    const bf16_t* b0 = Bt + (size_t)br0 * K + soff;
    const bf16_t* b1 = Bt + (size_t)br1 * K + soff;
    bf16_t* la = &As[tid * 8];   // byte off = tid*16 = wave_base + lane*16
    bf16_t* lb = &Bs[tid * 8];

    f32x4 acc[4][4];
    #pragma unroll
    for (int i = 0; i < 4; ++i)
        #pragma unroll
        for (int j = 0; j < 4; ++j)
            acc[i][j] = (f32x4){0.f, 0.f, 0.f, 0.f};

    for (int k0 = 0; k0 < K; k0 += 32) {
        glds16(a0 + k0, la);
        glds16(a1 + k0, la + 2048);
        glds16(b0 + k0, lb);
        glds16(b1 + k0, lb + 2048);
        __syncthreads();   // compiler drains vmcnt before s_barrier
        bf16x8 af[4], bfr[4];
        #pragma unroll
        for (int t = 0; t < 4; ++t) {
            af[t]  = *(const bf16x8*)&As[(wm + t * 16 + l16) * 32 + quad * 8];
            bfr[t] = *(const bf16x8*)&Bs[(wn + t * 16 + l16) * 32 + quad * 8];
        }
        #pragma unroll
        for (int i = 0; i < 4; ++i)
            #pragma unroll
            for (int j = 0; j < 4; ++j)
                acc[i][j] = __builtin_amdgcn_mfma_f32_16x16x32_bf16(af[i], bfr[j], acc[i][j], 0, 0, 0);
        __syncthreads();
    }

    #pragma unroll
    for (int i = 0; i < 4; ++i) {
        #pragma unroll
        for (int j = 0; j < 4; ++j) {
            #pragma unroll
            for (int r = 0; r < 4; ++r) {
                int row = bm + wm + i * 16 + quad * 4 + r;
                int col = bn + wn + j * 16 + l16;
                if (col < N) {
                    if (writef) Cf[(size_t)row * N + col] = acc[i][j][r];
                    else        Cb[(size_t)row * N + col] = (bf16_t)acc[i][j][r];
                }
            }
        }
    }
}

// ---------------- rmsnorm in-place over rows ----------------
__global__ __launch_bounds__(256) void rmsnorm_rows(
    bf16_t* __restrict__ X, const float* __restrict__ w, int N)
{
    int row = blockIdx.x;
    bf16_t* x = X + (size_t)row * N;
    float ss = 0.f;
    for (int i = threadIdx.x; i < N; i += 256) { float v = (float)x[i]; ss += v * v; }
    ss = block_reduce_sum_256(ss);
    float sc = rsqrtf(ss / (float)N + 1e-6f);
    for (int i = threadIdx.x; i < N; i += 256)
        x[i] = (bf16_t)((float)x[i] * sc * w[i]);
}

// ---------------- kv post ----------------
__global__ __launch_bounds__(256) void kv_post(
    const bf16_t* __restrict__ kvd, const float* __restrict__ w,
    const float* __restrict__ freqs,
    bf16_t* __restrict__ ckvn, bf16_t* __restrict__ kr)
{
    int row = blockIdx.x;
    const bf16_t* src = kvd + (size_t)row * (KVLORA + ROPE);
    float ss = 0.f;
    for (int i = threadIdx.x; i < KVLORA; i += 256) { float v = (float)src[i]; ss += v * v; }
    ss = block_reduce_sum_256(ss);
    float sc = rsqrtf(ss / (float)KVLORA + 1e-6f);
    for (int i = threadIdx.x; i < KVLORA; i += 256)
        ckvn[(size_t)row * KVLORA + i] = (bf16_t)((float)src[i] * sc * w[i]);
    if (threadIdx.x < 32) {
        int i = threadIdx.x;
        float f = freqs[row * 32 + i];
        float c = cosf(f), s = sinf(f);
        float x1 = (float)src[KVLORA + 2 * i], x2 = (float)src[KVLORA + 2 * i + 1];
        kr[(size_t)row * ROPE + 2 * i]     = (bf16_t)(x1 * c - x2 * s);
        kr[(size_t)row * ROPE + 2 * i + 1] = (bf16_t)(x1 * s + x2 * c);
    }
}

// ---------------- rope on q_rope in-place ----------------
__global__ void rope_q(bf16_t* __restrict__ qr, const float* __restrict__ freqs) {
    int idx = blockIdx.x * 256 + threadIdx.x;
    if (idx >= T_SEQ * NH * 32) return;
    int t = idx >> 9;
    int rem = idx & 511;
    int h = rem >> 5;
    int i = rem & 31;
    float f = freqs[t * 32 + i];
    float c = cosf(f), s = sinf(f);
    bf16_t* p = qr + (size_t)t * (NH * ROPE) + h * ROPE + 2 * i;
    float x1 = (float)p[0], x2 = (float)p[1];
    p[0] = (bf16_t)(x1 * c - x2 * s);
    p[1] = (bf16_t)(x1 * s + x2 * c);
}

// ---------------- split-K MFMA flash attention (causal, fixed-max softmax) ----------------
// v8: ALL staging via global_load_lds (async DMA, data never in VGPRs) -- kills the
// scratch-spill that dominated v5-v7 (reg-prefetch arrays went to scratch: 580MB/disp
// of spill-store traffic, immune to launch_bounds). LDS layouts are LINEAR (glds
// requirement); bank conflicts on the strided ds_reads are fixed by the rule-21
// both-sides swizzle: per-lane global source fetches chunk (ch ^ (row&7)), reads
// address chunk (ch ^ (row&7)) -- 16-way conflict -> 2-way (free).
#define P_STRIDE 72     // 64+8 bf16
__device__ inline int slot_base(int qt, int h) {
    int b = qt / CHUNK;
    return h * 120 + qt + 6 * b * (b - 1) + (qt - CHUNK * b) * b;
}
__global__ __launch_bounds__(256) void attn_v8(
    const bf16_t* __restrict__ QN, const bf16_t* __restrict__ QR,
    const bf16_t* __restrict__ KVU, const bf16_t* __restrict__ KR,
    const bf16_t* __restrict__ Vt,
    bf16_t* __restrict__ Opart, float* __restrict__ lpart)
{
    __shared__ __align__(16) bf16_t Kn[64 * 128];         // 16384 B (k_nope, swizzled)
    __shared__ __align__(16) bf16_t Kr[64 * 64];          //  8192 B (k_rope, swizzled)
    __shared__ __align__(16) bf16_t Vs[128 * 64];         // 16384 B (v^T, swizzled)
    __shared__ __align__(16) bf16_t Ps[4][16 * P_STRIDE]; //  9216 B

    int qt = blockIdx.x, cx = blockIdx.y, h = blockIdx.z;
    if (cx > qt / CHUNK) return;
    int slot = slot_base(qt, h) + cx;
    int kt0 = cx * CHUNK;
    int kt1 = min(qt + 1, kt0 + CHUNK);

    int tid = threadIdx.x;
    int w = tid >> 6, lane = tid & 63;
    int quad = lane >> 4, l16 = lane & 15;
    int qbase = qt * 64;

    // Q fragments straight from global into registers
    bf16x8 qf[6];
    {
        int qrow = qbase + w * 16 + l16;
        #pragma unroll
        for (int kk = 0; kk < 4; ++kk)
            qf[kk] = *(const bf16x8*)&QN[(size_t)qrow * (NH * NOPE) + h * NOPE + kk * 32 + quad * 8];
        #pragma unroll
        for (int kk = 4; kk < 6; ++kk)
            qf[kk] = *(const bf16x8*)&QR[(size_t)qrow * (NH * ROPE) + h * ROPE + (kk - 4) * 32 + quad * 8];
    }

    // per-lane pre-swizzled global source pointers for glds staging.
    // Kn: wave w stages rows [w*16, w*16+16) as 4 glds of 4 rows (16 chunks/row).
    //     lane -> row w*16 + i*4 + (lane>>4), phys chunk lane&15 holds logical
    //     chunk (lane&15) ^ (row&7); (row&7) = (lane>>4) for even i, 4+(lane>>4) odd.
    // Kr: wave w stages rows [w*16, w*16+16) as 2 glds of 8 rows (8 chunks/row);
    //     (row&7) = lane>>3 for all i.
    // Vs: wave w stages d-rows [w*32, w*32+32) as 4 glds of 8 rows (8 chunks/row).
    int l4 = lane >> 4, l3 = lane >> 3;
    const bf16_t* kn_e = KVU + (size_t)(kt0 * 64 + w * 16 + l4) * (NH * 256) + h * 256 + ((lane & 15) ^ l4) * 8;
    const bf16_t* kn_o = KVU + (size_t)(kt0 * 64 + w * 16 + l4) * (NH * 256) + h * 256 + ((lane & 15) ^ (4 + l4)) * 8;
    const bf16_t* krp  = KR  + (size_t)(kt0 * 64 + w * 16 + l3) * ROPE + ((lane & 7) ^ l3) * 8;
    const bf16_t* vp   = Vt  + ((size_t)h * VDIM + w * 32 + l3) * T_SEQ + kt0 * 64 + ((lane & 7) ^ l3) * 8;

    bf16x8 ones;
    #pragma unroll
    for (int i = 0; i < 8; ++i) ones[i] = (bf16_t)1.0f;

    f32x4 o[8];
    #pragma unroll
    for (int nt = 0; nt < 8; ++nt) o[nt] = (f32x4){0.f, 0.f, 0.f, 0.f};
    f32x4 lacc = (f32x4){0.f, 0.f, 0.f, 0.f};

    for (int kt = kt0; kt < kt1; ++kt) {
        int kbase = kt * 64;
        // async stage K (nope+rope) and V tiles; data bypasses VGPRs entirely
        #pragma unroll
        for (int i = 0; i < 4; ++i)
            glds16(((i & 1) ? kn_o : kn_e) + (size_t)i * 4 * (NH * 256), &Kn[(w * 4 + i) * 512]);
        #pragma unroll
        for (int i = 0; i < 2; ++i)
            glds16(krp + (size_t)i * 8 * ROPE, &Kr[(w * 2 + i) * 512]);
        #pragma unroll
        for (int i = 0; i < 4; ++i)
            glds16(vp + (size_t)i * 8 * T_SEQ, &Vs[(w * 4 + i) * 512]);
        kn_e += (size_t)64 * NH * 256;
        kn_o += (size_t)64 * NH * 256;
        krp  += 64 * ROPE;
        vp   += 64;
        __syncthreads();   // vmcnt drained before barrier -> tiles visible

        // S = Q K^T : 4 col-tiles x (4 nope + 2 rope) k-steps, swizzled reads
        f32x4 S[4];
        #pragma unroll
        for (int c = 0; c < 4; ++c) S[c] = (f32x4){0.f, 0.f, 0.f, 0.f};
        #pragma unroll
        for (int kk = 0; kk < 4; ++kk) {
            #pragma unroll
            for (int c = 0; c < 4; ++c) {
                bf16x8 kf = *(const bf16x8*)&Kn[(c * 16 + l16) * 128 + (((kk * 4 + quad) ^ (l16 & 7)) * 8)];
                S[c] = __builtin_amdgcn_mfma_f32_16x16x32_bf16(qf[kk], kf, S[c], 0, 0, 0);
            }
        }
        #pragma unroll
        for (int kk = 4; kk < 6; ++kk) {
            #pragma unroll
            for (int c = 0; c < 4; ++c) {
                bf16x8 kf = *(const bf16x8*)&Kr[(c * 16 + l16) * 64 + ((((kk - 4) * 4 + quad) ^ (l16 & 7)) * 8)];
                S[c] = __builtin_amdgcn_mfma_f32_16x16x32_bf16(qf[kk], kf, S[c], 0, 0, 0);
            }
        }

        // fixed-max softmax: p = exp(s*SCALE) (bounded; shift-invariance -> additive splits)
        #pragma unroll
        for (int c = 0; c < 4; ++c) {
            #pragma unroll
            for (int j = 0; j < 4; ++j) {
                int col = kbase + c * 16 + l16;
                int grow = qbase + w * 16 + quad * 4 + j;
                float p = (col <= grow) ? __expf(S[c][j] * SCALE) : 0.f;
                Ps[w][(quad * 4 + j) * P_STRIDE + c * 16 + l16] = (bf16_t)p;
            }
        }
        __asm__ volatile("s_waitcnt lgkmcnt(0)" ::: "memory");

        bf16x8 pf0 = *(const bf16x8*)&Ps[w][l16 * P_STRIDE + quad * 8];
        bf16x8 pf1 = *(const bf16x8*)&Ps[w][l16 * P_STRIDE + 32 + quad * 8];
        lacc = __builtin_amdgcn_mfma_f32_16x16x32_bf16(pf0, ones, lacc, 0, 0, 0);
        lacc = __builtin_amdgcn_mfma_f32_16x16x32_bf16(pf1, ones, lacc, 0, 0, 0);

        // O += P V : V fragments from LDS (swizzled reads)
        #pragma unroll
        for (int kk2 = 0; kk2 < 2; ++kk2) {
            bf16x8 pf = kk2 ? pf1 : pf0;
            #pragma unroll
            for (int nt = 0; nt < 8; ++nt) {
                bf16x8 vf = *(const bf16x8*)&Vs[(nt * 16 + l16) * 64 + (((kk2 * 4 + quad) ^ (l16 & 7)) * 8)];
                o[nt] = __builtin_amdgcn_mfma_f32_16x16x32_bf16(pf, vf, o[nt], 0, 0, 0);
            }
        }
        __syncthreads();   // all reads done before next restage
    }

    // write raw partials (no normalization)
    #pragma unroll
    for (int nt = 0; nt < 8; ++nt)
        #pragma unroll
        for (int j = 0; j < 4; ++j)
            Opart[(size_t)slot * 8192 + (w * 16 + quad * 4 + j) * 128 + nt * 16 + l16] = (bf16_t)o[nt][j];
    if (l16 == 0) {
        #pragma unroll
        for (int j = 0; j < 4; ++j)
            lpart[slot * 64 + w * 16 + quad * 4 + j] = lacc[j];
    }
}

// ---------------- combine: sum partials, normalize, write ao ----------------
__global__ __launch_bounds__(256) void attn_combine(
    const bf16_t* __restrict__ Opart, const float* __restrict__ lpart,
    bf16_t* __restrict__ AO)
{
    int qt = blockIdx.x, h = blockIdx.y;
    int nch = qt / CHUNK + 1;
    int base = slot_base(qt, h);
    int r = threadIdx.x >> 2, c0 = (threadIdx.x & 3) * 32;

    float acc[32];
    #pragma unroll
    for (int i = 0; i < 32; ++i) acc[i] = 0.f;
    float lsum = 0.f;
    for (int ch = 0; ch < nch; ++ch) {
        int slot = base + ch;
        const bf16_t* p = &Opart[(size_t)slot * 8192 + r * 128 + c0];
        #pragma unroll
        for (int v = 0; v < 4; ++v) {
            bf16x8 u = *(const bf16x8*)&p[v * 8];
            #pragma unroll
            for (int e = 0; e < 8; ++e) acc[v * 8 + e] += (float)u[e];
        }
        lsum += lpart[slot * 64 + r];
    }
    float inv = 1.0f / lsum;
    bf16_t* dst = AO + (size_t)(qt * 64 + r) * (NH * VDIM) + h * VDIM + c0;
    #pragma unroll
    for (int v = 0; v < 4; ++v) {
        bf16_t tmp[8];
        #pragma unroll
        for (int e = 0; e < 8; ++e) tmp[e] = (bf16_t)(acc[v * 8 + e] * inv);
        *(uint4*)&dst[v * 8] = *(const uint4*)tmp;
    }
}

// ---------------- launch ----------------
extern "C" void kernel_launch(void* const* d_in, const int* in_sizes, int n_in,
                              void* d_out, int out_size, void* d_ws, size_t ws_size,
                              hipStream_t stream) {
    const float* x        = (const float*)d_in[0];
    const float* freqs    = (const float*)d_in[1];
    // d_in[2] = mask (unused; causality applied analytically)
    const float* wq_down  = (const float*)d_in[3];
    const float* q_norm_w = (const float*)d_in[4];
    const float* wq_nope  = (const float*)d_in[5];
    const float* wq_rope  = (const float*)d_in[6];
    const float* wkv_down = (const float*)d_in[7];
    const float* kv_norm_w= (const float*)d_in[8];
    const float* wkv_up   = (const float*)d_in[9];
    const float* wo       = (const float*)d_in[10];
    float* out = (float*)d_out;

    bf16_t* ws = (bf16_t*)d_ws;
    // ---- pool region (two time-disjoint views), 25,493,504 bf16 elems ----
    // A-view: pre-attention transients
    bf16_t* xb     = ws;                     // 3072*2048
    bf16_t* wqd_t  = xb     + 6291456;       // [1536][2048]
    bf16_t* wkvd_t = wqd_t  + 3145728;       // [576][2048]
    bf16_t* wqn_t  = wkvd_t + 1179648;       // [2048][1536]
    bf16_t* wqr_t  = wqn_t  + 3145728;       // [1024][1536]
    bf16_t* wkvu_t = wqr_t  + 1572864;       // [4096][512]
    bf16_t* t1     = wkvu_t + 2097152;       // 3072*1536 (q_lat)
    bf16_t* kvd    = t1     + 4718592;       // 3072*576
    bf16_t* ckvn   = kvd    + 1769472;       // 3072*512  (ends at 25,493,504)
    // B-view: attention partials + ao
    bf16_t* Opart  = ws;                     // 1920 slots * 8192
    float*  lpart  = (float*)(ws + 15728640);// 1920 * 64 fp32
    bf16_t* ao     = ws + 15728640 + 245760; // 3072*2048
    // ---- tail region (long-lived) ----
    bf16_t* wo_t   = ws    + 25493504;       // [2048][2048]
    bf16_t* kr     = wo_t  + 4194304;        // 3072*64
    bf16_t* qn     = kr    + 196608;         // 3072*2048
    bf16_t* qr     = qn    + 6291456;        // 3072*1024
    bf16_t* kvu    = qr    + 3145728;        // 3072*4096
    bf16_t* vt     = kvu   + 12582912;       // [16][128][3072]  (total 58,195,968)

    // converts + weight transposes
    f2b_kernel<<<T_SEQ * DIM / 4 / 256, 256, 0, stream>>>(x, xb, T_SEQ * DIM);
    transp_kernel<<<dim3(QLORA / 32, DIM / 32), 256, 0, stream>>>(wq_down, wqd_t, DIM, QLORA);
    transp_kernel<<<dim3((KVLORA + ROPE) / 32, DIM / 32), 256, 0, stream>>>(wkv_down, wkvd_t, DIM, KVLORA + ROPE);
    transp_kernel<<<dim3(NH * NOPE / 32, QLORA / 32), 256, 0, stream>>>(wq_nope, wqn_t, QLORA, NH * NOPE);
    transp_kernel<<<dim3(NH * ROPE / 32, QLORA / 32), 256, 0, stream>>>(wq_rope, wqr_t, QLORA, NH * ROPE);
    transp_kernel<<<dim3(NH * 256 / 32, KVLORA / 32), 256, 0, stream>>>(wkv_up, wkvu_t, KVLORA, NH * 256);
    transp_kernel<<<dim3(DIM / 32, DIM / 32), 256, 0, stream>>>(wo, wo_t, DIM, DIM);

    // down-projections
    gemm_mfma<<<dim3(QLORA / 128, T_SEQ / 128), 256, 0, stream>>>(xb, wqd_t, nullptr, t1, T_SEQ, QLORA, DIM, 0);
    gemm_mfma<<<dim3(5, T_SEQ / 128), 256, 0, stream>>>(xb, wkvd_t, nullptr, kvd, T_SEQ, KVLORA + ROPE, DIM, 0);

    rmsnorm_rows<<<T_SEQ, 256, 0, stream>>>(t1, q_norm_w, QLORA);
    kv_post<<<T_SEQ, 256, 0, stream>>>(kvd, kv_norm_w, freqs, ckvn, kr);

    // up-projections
    gemm_mfma<<<dim3(NH * NOPE / 128, T_SEQ / 128), 256, 0, stream>>>(t1, wqn_t, nullptr, qn, T_SEQ, NH * NOPE, QLORA, 0);
    gemm_mfma<<<dim3(NH * ROPE / 128, T_SEQ / 128), 256, 0, stream>>>(t1, wqr_t, nullptr, qr, T_SEQ, NH * ROPE, QLORA, 0);
    rope_q<<<(T_SEQ * NH * 32 + 255) / 256, 256, 0, stream>>>(qr, freqs);
    gemm_mfma<<<dim3(NH * 256 / 128, T_SEQ / 128), 256, 0, stream>>>(ckvn, wkvu_t, nullptr, kvu, T_SEQ, NH * 256, KVLORA, 0);

    // V transpose for attention B-operand
    vt_transp<<<dim3(T_SEQ / 32, VDIM / 32, NH), 256, 0, stream>>>(kvu, vt);

    // split-K attention + combine
    attn_v8<<<dim3(T_SEQ / 64, 4, NH), 256, 0, stream>>>(qn, qr, kvu, kr, vt, Opart, lpart);
    attn_combine<<<dim3(T_SEQ / 64, NH), 256, 0, stream>>>(Opart, lpart, ao);

    // output projection (fp32 out)
    gemm_mfma<<<dim3(DIM / 128, T_SEQ / 128), 256, 0, stream>>>(ao, wo_t, out, nullptr, T_SEQ, DIM, DIM, 1);
}

// Round 5
// 476.841 us; speedup vs baseline: 1.7016x; 1.2006x over previous
//
#include <hip/hip_runtime.h>
#include <hip/hip_bf16.h>

typedef __bf16 bf16_t;
typedef __bf16 bf16x8 __attribute__((ext_vector_type(8)));
typedef float f32x4 __attribute__((ext_vector_type(4)));

// Problem constants
#define T_SEQ 3072
#define DIM 2048
#define NH 16
#define QLORA 1536
#define KVLORA 512
#define NOPE 128
#define ROPE 64
#define VDIM 128
#define HD 192          // NOPE+ROPE
#define SCALE 0.07216878364870323f  // 192^-0.5
#define CHUNK 12        // k-tiles (of 64 keys) per attention block

// fused-buffer strides
#define T1KV_LD 2112    // [3072][1536 q_lat | 512 c_kv | 64 k_rope]
#define QNR_LD 3072     // [3072][2048 q_nope | 1024 q_rope]

// ---------------- helpers ----------------
__device__ inline float wave_reduce_sum(float v) {
    #pragma unroll
    for (int off = 32; off > 0; off >>= 1) v += __shfl_down(v, off);
    return v;
}

__device__ inline float block_reduce_sum_256(float v) {
    __shared__ float red[4];
    int lane = threadIdx.x & 63, w = threadIdx.x >> 6;
    v = wave_reduce_sum(v);
    if (lane == 0) red[w] = v;
    __syncthreads();
    if (threadIdx.x == 0) red[0] = red[0] + red[1] + red[2] + red[3];
    __syncthreads();
    return red[0];
}

// async global->LDS, 16B per lane. LDS dest is wave-uniform base + lane*16 (linear).
// Global source address is per-lane (pre-swizzle it to realize swizzled LDS layouts).
__device__ inline void glds16(const bf16_t* g, bf16_t* l) {
    __builtin_amdgcn_global_load_lds(
        (const __attribute__((address_space(1))) unsigned int*)g,
        (__attribute__((address_space(3))) unsigned int*)l, 16, 0, 0);
}

// ---------------- fp32 -> bf16 convert ----------------
__global__ void f2b_kernel(const float* __restrict__ in, bf16_t* __restrict__ out, int n) {
    int i = (blockIdx.x * 256 + threadIdx.x) * 4;
    if (i < n) {
        float4 v = *(const float4*)&in[i];
        bf16_t o[4] = {(bf16_t)v.x, (bf16_t)v.y, (bf16_t)v.z, (bf16_t)v.w};
        *(uint2*)&out[i] = *(const uint2*)o;
    }
}

// ---------------- fp32 [K][N] -> bf16 [N][K] transpose-convert ----------------
__global__ __launch_bounds__(256) void transp_kernel(
    const float* __restrict__ in, bf16_t* __restrict__ out, int K, int N)
{
    __shared__ float tile[32][33];
    int k0 = blockIdx.y * 32, n0 = blockIdx.x * 32;
    int tx = threadIdx.x & 31, ty = threadIdx.x >> 5;
    #pragma unroll
    for (int i = 0; i < 4; ++i)
        tile[ty + i * 8][tx] = in[(size_t)(k0 + ty + i * 8) * N + n0 + tx];
    __syncthreads();
    #pragma unroll
    for (int i = 0; i < 4; ++i)
        out[(size_t)(n0 + ty + i * 8) * K + k0 + tx] = (bf16_t)tile[tx][ty + i * 8];
}

// ---------------- bf16 kvu V-part -> vt[h][d][t] transpose ----------------
__global__ __launch_bounds__(256) void vt_transp(
    const bf16_t* __restrict__ kvu, bf16_t* __restrict__ vt)
{
    __shared__ bf16_t tile[32][34];
    int t0 = blockIdx.x * 32, d0 = blockIdx.y * 32, h = blockIdx.z;
    int tx = threadIdx.x & 31, ty = threadIdx.x >> 5;
    #pragma unroll
    for (int i = 0; i < 4; ++i)
        tile[ty + i * 8][tx] = kvu[(size_t)(t0 + ty + i * 8) * (NH * 256) + h * 256 + NOPE + d0 + tx];
    __syncthreads();
    #pragma unroll
    for (int i = 0; i < 4; ++i)
        vt[((size_t)h * VDIM + d0 + ty + i * 8) * T_SEQ + t0 + tx] = tile[tx][ty + i * 8];
}

// ---------------- MFMA GEMM: C[M,N] = A[M,K](bf16, row-stride lda) x Bt[N,K](bf16, row-stride ldb) ----------------
// v2: 128x128 tile, BK=32, glds staging with LDS double-buffer + counted vmcnt(4)
// (T3/T4 minimal form). Loads for tile t+1 stay in flight across both barriers of
// tile t -- critical here because several grids are ~1 block/CU, so the implicit
// multi-block overlap that normally hides the vmcnt(0) barrier-drain is absent.
__global__ __launch_bounds__(256) void gemm_mfma(
    const bf16_t* __restrict__ A, const bf16_t* __restrict__ Bt,
    float* __restrict__ Cf, bf16_t* __restrict__ Cb,
    int M, int N, int K, int lda, int ldb, int ldc, int writef)
{
    __shared__ __align__(16) bf16_t As[2][128 * 32];
    __shared__ __align__(16) bf16_t Bs[2][128 * 32];
    int tid = threadIdx.x;
    int w = tid >> 6, lane = tid & 63;
    int quad = lane >> 4, l16 = lane & 15;
    int bm = blockIdx.y * 128, bn = blockIdx.x * 128;
    int wm = (w & 1) * 64, wn = (w >> 1) * 64;

    // staging coords: thread stages rows srow and srow+64, 16B chunk soff
    int srow = tid >> 2, soff = (tid & 3) * 8;
    const bf16_t* a0 = A + (size_t)(bm + srow) * lda + soff;
    const bf16_t* a1 = A + (size_t)(bm + 64 + srow) * lda + soff;
    int br0 = bn + srow;      if (br0 >= N) br0 = N - 1;   // clamp (cols >= N never written)
    int br1 = bn + 64 + srow; if (br1 >= N) br1 = N - 1;
    const bf16_t* b0 = Bt + (size_t)br0 * ldb + soff;
    const bf16_t* b1 = Bt + (size_t)br1 * ldb + soff;

    f32x4 acc[4][4];
    #pragma unroll
    for (int i = 0; i < 4; ++i)
        #pragma unroll
        for (int j = 0; j < 4; ++j)
            acc[i][j] = (f32x4){0.f, 0.f, 0.f, 0.f};

    int nk = K >> 5;
    // prologue: stage tile 0 into buffer 0
    glds16(a0, &As[0][tid * 8]);
    glds16(a1, &As[0][tid * 8 + 2048]);
    glds16(b0, &Bs[0][tid * 8]);
    glds16(b1, &Bs[0][tid * 8 + 2048]);
    a0 += 32; a1 += 32; b0 += 32; b1 += 32;

    for (int t = 0; t < nk; ++t) {
        int cur = t & 1;
        if (t + 1 < nk) {
            int nxt = cur ^ 1;
            // issue next tile's loads; they remain in flight across the barriers
            glds16(a0, &As[nxt][tid * 8]);
            glds16(a1, &As[nxt][tid * 8 + 2048]);
            glds16(b0, &Bs[nxt][tid * 8]);
            glds16(b1, &Bs[nxt][tid * 8 + 2048]);
            a0 += 32; a1 += 32; b0 += 32; b1 += 32;
            asm volatile("s_waitcnt vmcnt(4)" ::: "memory");   // tile t's 4 loads done
        } else {
            asm volatile("s_waitcnt vmcnt(0)" ::: "memory");   // drain for last tile
        }
        __builtin_amdgcn_s_barrier();          // all waves' tile-t loads landed
        __builtin_amdgcn_sched_barrier(0);     // no ds_read hoisted above barrier

        bf16x8 af[4], bfr[4];
        #pragma unroll
        for (int t4 = 0; t4 < 4; ++t4) {
            af[t4]  = *(const bf16x8*)&As[cur][(wm + t4 * 16 + l16) * 32 + quad * 8];
            bfr[t4] = *(const bf16x8*)&Bs[cur][(wn + t4 * 16 + l16) * 32 + quad * 8];
        }
        #pragma unroll
        for (int i = 0; i < 4; ++i)
            #pragma unroll
            for (int j = 0; j < 4; ++j)
                acc[i][j] = __builtin_amdgcn_mfma_f32_16x16x32_bf16(af[i], bfr[j], acc[i][j], 0, 0, 0);

        __builtin_amdgcn_sched_barrier(0);     // no next-STAGE glds hoisted above this point
        __builtin_amdgcn_s_barrier();          // all waves done reading buf[cur]
    }

    #pragma unroll
    for (int i = 0; i < 4; ++i) {
        #pragma unroll
        for (int j = 0; j < 4; ++j) {
            #pragma unroll
            for (int r = 0; r < 4; ++r) {
                int row = bm + wm + i * 16 + quad * 4 + r;
                int col = bn + wn + j * 16 + l16;
                if (col < N) {
                    if (writef) Cf[(size_t)row * ldc + col] = acc[i][j][r];
                    else        Cb[(size_t)row * ldc + col] = (bf16_t)acc[i][j][r];
                }
            }
        }
    }
}

// ---------------- rmsnorm over first N cols of rows with stride ld ----------------
__global__ __launch_bounds__(256) void rmsnorm_rows(
    bf16_t* __restrict__ X, const float* __restrict__ w, int N, int ld)
{
    int row = blockIdx.x;
    bf16_t* x = X + (size_t)row * ld;
    float ss = 0.f;
    for (int i = threadIdx.x; i < N; i += 256) { float v = (float)x[i]; ss += v * v; }
    ss = block_reduce_sum_256(ss);
    float sc = rsqrtf(ss / (float)N + 1e-6f);
    for (int i = threadIdx.x; i < N; i += 256)
        x[i] = (bf16_t)((float)x[i] * sc * w[i]);
}

// ---------------- kv post: src = fused t1kv rows at col offset 1536 ----------------
__global__ __launch_bounds__(256) void kv_post(
    const bf16_t* __restrict__ kvd, const float* __restrict__ w,
    const float* __restrict__ freqs,
    bf16_t* __restrict__ ckvn, bf16_t* __restrict__ kr)
{
    int row = blockIdx.x;
    const bf16_t* src = kvd + (size_t)row * T1KV_LD;   // points at c_kv|k_rope block
    float ss = 0.f;
    for (int i = threadIdx.x; i < KVLORA; i += 256) { float v = (float)src[i]; ss += v * v; }
    ss = block_reduce_sum_256(ss);
    float sc = rsqrtf(ss / (float)KVLORA + 1e-6f);
    for (int i = threadIdx.x; i < KVLORA; i += 256)
        ckvn[(size_t)row * KVLORA + i] = (bf16_t)((float)src[i] * sc * w[i]);
    if (threadIdx.x < 32) {
        int i = threadIdx.x;
        float f = freqs[row * 32 + i];
        float c = cosf(f), s = sinf(f);
        float x1 = (float)src[KVLORA + 2 * i], x2 = (float)src[KVLORA + 2 * i + 1];
        kr[(size_t)row * ROPE + 2 * i]     = (bf16_t)(x1 * c - x2 * s);
        kr[(size_t)row * ROPE + 2 * i + 1] = (bf16_t)(x1 * s + x2 * c);
    }
}

// ---------------- rope on q_rope (cols 2048.. of qnr) in-place ----------------
__global__ void rope_q(bf16_t* __restrict__ qr, const float* __restrict__ freqs) {
    int idx = blockIdx.x * 256 + threadIdx.x;
    if (idx >= T_SEQ * NH * 32) return;
    int t = idx >> 9;
    int rem = idx & 511;
    int h = rem >> 5;
    int i = rem & 31;
    float f = freqs[t * 32 + i];
    float c = cosf(f), s = sinf(f);
    bf16_t* p = qr + (size_t)t * QNR_LD + h * ROPE + 2 * i;
    float x1 = (float)p[0], x2 = (float)p[1];
    p[0] = (bf16_t)(x1 * c - x2 * s);
    p[1] = (bf16_t)(x1 * s + x2 * c);
}

// ---------------- split-K MFMA flash attention (causal, fixed-max softmax) ----------------
// v8 structure (all staging via global_load_lds, rule-21 both-sides swizzle);
// only change: Q reads come from the fused qnr buffer (row stride 3072).
#define P_STRIDE 72     // 64+8 bf16
__device__ inline int slot_base(int qt, int h) {
    int b = qt / CHUNK;
    return h * 120 + qt + 6 * b * (b - 1) + (qt - CHUNK * b) * b;
}
__global__ __launch_bounds__(256) void attn_v8(
    const bf16_t* __restrict__ QNR,
    const bf16_t* __restrict__ KVU, const bf16_t* __restrict__ KR,
    const bf16_t* __restrict__ Vt,
    bf16_t* __restrict__ Opart, float* __restrict__ lpart)
{
    __shared__ __align__(16) bf16_t Kn[64 * 128];         // 16384 B (k_nope, swizzled)
    __shared__ __align__(16) bf16_t Kr[64 * 64];          //  8192 B (k_rope, swizzled)
    __shared__ __align__(16) bf16_t Vs[128 * 64];         // 16384 B (v^T, swizzled)
    __shared__ __align__(16) bf16_t Ps[4][16 * P_STRIDE]; //  9216 B

    int qt = blockIdx.x, cx = blockIdx.y, h = blockIdx.z;
    if (cx > qt / CHUNK) return;
    int slot = slot_base(qt, h) + cx;
    int kt0 = cx * CHUNK;
    int kt1 = min(qt + 1, kt0 + CHUNK);

    int tid = threadIdx.x;
    int w = tid >> 6, lane = tid & 63;
    int quad = lane >> 4, l16 = lane & 15;
    int qbase = qt * 64;

    // Q fragments straight from global into registers (fused layout)
    bf16x8 qf[6];
    {
        int qrow = qbase + w * 16 + l16;
        #pragma unroll
        for (int kk = 0; kk < 4; ++kk)
            qf[kk] = *(const bf16x8*)&QNR[(size_t)qrow * QNR_LD + h * NOPE + kk * 32 + quad * 8];
        #pragma unroll
        for (int kk = 4; kk < 6; ++kk)
            qf[kk] = *(const bf16x8*)&QNR[(size_t)qrow * QNR_LD + (NH * NOPE) + h * ROPE + (kk - 4) * 32 + quad * 8];
    }

    // per-lane pre-swizzled global source pointers for glds staging (see v8 notes)
    int l4 = lane >> 4, l3 = lane >> 3;
    const bf16_t* kn_e = KVU + (size_t)(kt0 * 64 + w * 16 + l4) * (NH * 256) + h * 256 + ((lane & 15) ^ l4) * 8;
    const bf16_t* kn_o = KVU + (size_t)(kt0 * 64 + w * 16 + l4) * (NH * 256) + h * 256 + ((lane & 15) ^ (4 + l4)) * 8;
    const bf16_t* krp  = KR  + (size_t)(kt0 * 64 + w * 16 + l3) * ROPE + ((lane & 7) ^ l3) * 8;
    const bf16_t* vp   = Vt  + ((size_t)h * VDIM + w * 32 + l3) * T_SEQ + kt0 * 64 + ((lane & 7) ^ l3) * 8;

    bf16x8 ones;
    #pragma unroll
    for (int i = 0; i < 8; ++i) ones[i] = (bf16_t)1.0f;

    f32x4 o[8];
    #pragma unroll
    for (int nt = 0; nt < 8; ++nt) o[nt] = (f32x4){0.f, 0.f, 0.f, 0.f};
    f32x4 lacc = (f32x4){0.f, 0.f, 0.f, 0.f};

    for (int kt = kt0; kt < kt1; ++kt) {
        int kbase = kt * 64;
        // async stage K (nope+rope) and V tiles; data bypasses VGPRs entirely
        #pragma unroll
        for (int i = 0; i < 4; ++i)
            glds16(((i & 1) ? kn_o : kn_e) + (size_t)i * 4 * (NH * 256), &Kn[(w * 4 + i) * 512]);
        #pragma unroll
        for (int i = 0; i < 2; ++i)
            glds16(krp + (size_t)i * 8 * ROPE, &Kr[(w * 2 + i) * 512]);
        #pragma unroll
        for (int i = 0; i < 4; ++i)
            glds16(vp + (size_t)i * 8 * T_SEQ, &Vs[(w * 4 + i) * 512]);
        kn_e += (size_t)64 * NH * 256;
        kn_o += (size_t)64 * NH * 256;
        krp  += 64 * ROPE;
        vp   += 64;
        __syncthreads();   // vmcnt drained before barrier -> tiles visible

        // S = Q K^T : 4 col-tiles x (4 nope + 2 rope) k-steps, swizzled reads
        f32x4 S[4];
        #pragma unroll
        for (int c = 0; c < 4; ++c) S[c] = (f32x4){0.f, 0.f, 0.f, 0.f};
        #pragma unroll
        for (int kk = 0; kk < 4; ++kk) {
            #pragma unroll
            for (int c = 0; c < 4; ++c) {
                bf16x8 kf = *(const bf16x8*)&Kn[(c * 16 + l16) * 128 + (((kk * 4 + quad) ^ (l16 & 7)) * 8)];
                S[c] = __builtin_amdgcn_mfma_f32_16x16x32_bf16(qf[kk], kf, S[c], 0, 0, 0);
            }
        }
        #pragma unroll
        for (int kk = 4; kk < 6; ++kk) {
            #pragma unroll
            for (int c = 0; c < 4; ++c) {
                bf16x8 kf = *(const bf16x8*)&Kr[(c * 16 + l16) * 64 + ((((kk - 4) * 4 + quad) ^ (l16 & 7)) * 8)];
                S[c] = __builtin_amdgcn_mfma_f32_16x16x32_bf16(qf[kk], kf, S[c], 0, 0, 0);
            }
        }

        // fixed-max softmax: p = exp(s*SCALE) (bounded; shift-invariance -> additive splits)
        #pragma unroll
        for (int c = 0; c < 4; ++c) {
            #pragma unroll
            for (int j = 0; j < 4; ++j) {
                int col = kbase + c * 16 + l16;
                int grow = qbase + w * 16 + quad * 4 + j;
                float p = (col <= grow) ? __expf(S[c][j] * SCALE) : 0.f;
                Ps[w][(quad * 4 + j) * P_STRIDE + c * 16 + l16] = (bf16_t)p;
            }
        }
        __asm__ volatile("s_waitcnt lgkmcnt(0)" ::: "memory");

        bf16x8 pf0 = *(const bf16x8*)&Ps[w][l16 * P_STRIDE + quad * 8];
        bf16x8 pf1 = *(const bf16x8*)&Ps[w][l16 * P_STRIDE + 32 + quad * 8];
        lacc = __builtin_amdgcn_mfma_f32_16x16x32_bf16(pf0, ones, lacc, 0, 0, 0);
        lacc = __builtin_amdgcn_mfma_f32_16x16x32_bf16(pf1, ones, lacc, 0, 0, 0);

        // O += P V : V fragments from LDS (swizzled reads)
        #pragma unroll
        for (int kk2 = 0; kk2 < 2; ++kk2) {
            bf16x8 pf = kk2 ? pf1 : pf0;
            #pragma unroll
            for (int nt = 0; nt < 8; ++nt) {
                bf16x8 vf = *(const bf16x8*)&Vs[(nt * 16 + l16) * 64 + (((kk2 * 4 + quad) ^ (l16 & 7)) * 8)];
                o[nt] = __builtin_amdgcn_mfma_f32_16x16x32_bf16(pf, vf, o[nt], 0, 0, 0);
            }
        }
        __syncthreads();   // all reads done before next restage
    }

    // write raw partials (no normalization)
    #pragma unroll
    for (int nt = 0; nt < 8; ++nt)
        #pragma unroll
        for (int j = 0; j < 4; ++j)
            Opart[(size_t)slot * 8192 + (w * 16 + quad * 4 + j) * 128 + nt * 16 + l16] = (bf16_t)o[nt][j];
    if (l16 == 0) {
        #pragma unroll
        for (int j = 0; j < 4; ++j)
            lpart[slot * 64 + w * 16 + quad * 4 + j] = lacc[j];
    }
}

// ---------------- combine: sum partials, normalize, write ao ----------------
__global__ __launch_bounds__(256) void attn_combine(
    const bf16_t* __restrict__ Opart, const float* __restrict__ lpart,
    bf16_t* __restrict__ AO)
{
    int qt = blockIdx.x, h = blockIdx.y;
    int nch = qt / CHUNK + 1;
    int base = slot_base(qt, h);
    int r = threadIdx.x >> 2, c0 = (threadIdx.x & 3) * 32;

    float acc[32];
    #pragma unroll
    for (int i = 0; i < 32; ++i) acc[i] = 0.f;
    float lsum = 0.f;
    for (int ch = 0; ch < nch; ++ch) {
        int slot = base + ch;
        const bf16_t* p = &Opart[(size_t)slot * 8192 + r * 128 + c0];
        #pragma unroll
        for (int v = 0; v < 4; ++v) {
            bf16x8 u = *(const bf16x8*)&p[v * 8];
            #pragma unroll
            for (int e = 0; e < 8; ++e) acc[v * 8 + e] += (float)u[e];
        }
        lsum += lpart[slot * 64 + r];
    }
    float inv = 1.0f / lsum;
    bf16_t* dst = AO + (size_t)(qt * 64 + r) * (NH * VDIM) + h * VDIM + c0;
    #pragma unroll
    for (int v = 0; v < 4; ++v) {
        bf16_t tmp[8];
        #pragma unroll
        for (int e = 0; e < 8; ++e) tmp[e] = (bf16_t)(acc[v * 8 + e] * inv);
        *(uint4*)&dst[v * 8] = *(const uint4*)tmp;
    }
}

// ---------------- launch ----------------
extern "C" void kernel_launch(void* const* d_in, const int* in_sizes, int n_in,
                              void* d_out, int out_size, void* d_ws, size_t ws_size,
                              hipStream_t stream) {
    const float* x        = (const float*)d_in[0];
    const float* freqs    = (const float*)d_in[1];
    // d_in[2] = mask (unused; causality applied analytically)
    const float* wq_down  = (const float*)d_in[3];
    const float* q_norm_w = (const float*)d_in[4];
    const float* wq_nope  = (const float*)d_in[5];
    const float* wq_rope  = (const float*)d_in[6];
    const float* wkv_down = (const float*)d_in[7];
    const float* kv_norm_w= (const float*)d_in[8];
    const float* wkv_up   = (const float*)d_in[9];
    const float* wo       = (const float*)d_in[10];
    float* out = (float*)d_out;

    bf16_t* ws = (bf16_t*)d_ws;
    // ---- pool region (two time-disjoint views), 25,493,504 bf16 elems ----
    // A-view: pre-attention transients
    bf16_t* xb     = ws;                     // 3072*2048
    bf16_t* wqd_t  = xb     + 6291456;       // [1536][2048]  \ contiguous pair ->
    bf16_t* wkvd_t = wqd_t  + 3145728;       // [576][2048]   / fused Bt, N=2112
    bf16_t* wqn_t  = wkvd_t + 1179648;       // [2048][1536]  \ contiguous pair ->
    bf16_t* wqr_t  = wqn_t  + 3145728;       // [1024][1536]  / fused Bt, N=3072
    bf16_t* wkvu_t = wqr_t  + 1572864;       // [4096][512]
    bf16_t* t1kv   = wkvu_t + 2097152;       // [3072][2112] fused q_lat|c_kv|k_rope
    bf16_t* ckvn   = t1kv   + 6488064;       // 3072*512  (ends at 25,493,504)
    // B-view: attention partials + ao
    bf16_t* Opart  = ws;                     // 1920 slots * 8192
    float*  lpart  = (float*)(ws + 15728640);// 1920 * 64 fp32
    bf16_t* ao     = ws + 15728640 + 245760; // 3072*2048
    // ---- tail region (long-lived) ----
    bf16_t* wo_t   = ws    + 25493504;       // [2048][2048]
    bf16_t* kr     = wo_t  + 4194304;        // 3072*64
    bf16_t* qnr    = kr    + 196608;         // [3072][3072] fused q_nope|q_rope
    bf16_t* kvu    = qnr   + 9437184;        // 3072*4096
    bf16_t* vt     = kvu   + 12582912;       // [16][128][3072]  (total 58,195,968)

    // converts + weight transposes
    f2b_kernel<<<T_SEQ * DIM / 4 / 256, 256, 0, stream>>>(x, xb, T_SEQ * DIM);
    transp_kernel<<<dim3(QLORA / 32, DIM / 32), 256, 0, stream>>>(wq_down, wqd_t, DIM, QLORA);
    transp_kernel<<<dim3((KVLORA + ROPE) / 32, DIM / 32), 256, 0, stream>>>(wkv_down, wkvd_t, DIM, KVLORA + ROPE);
    transp_kernel<<<dim3(NH * NOPE / 32, QLORA / 32), 256, 0, stream>>>(wq_nope, wqn_t, QLORA, NH * NOPE);
    transp_kernel<<<dim3(NH * ROPE / 32, QLORA / 32), 256, 0, stream>>>(wq_rope, wqr_t, QLORA, NH * ROPE);
    transp_kernel<<<dim3(NH * 256 / 32, KVLORA / 32), 256, 0, stream>>>(wkv_up, wkvu_t, KVLORA, NH * 256);
    transp_kernel<<<dim3(DIM / 32, DIM / 32), 256, 0, stream>>>(wo, wo_t, DIM, DIM);

    // fused down-projection: [q_lat | c_kv | k_rope], N=2112, grid 17x24=408
    gemm_mfma<<<dim3(17, T_SEQ / 128), 256, 0, stream>>>(
        xb, wqd_t, nullptr, t1kv, T_SEQ, 2112, DIM, DIM, DIM, T1KV_LD, 0);

    rmsnorm_rows<<<T_SEQ, 256, 0, stream>>>(t1kv, q_norm_w, QLORA, T1KV_LD);
    kv_post<<<T_SEQ, 256, 0, stream>>>(t1kv + QLORA, kv_norm_w, freqs, ckvn, kr);

    // fused q up-projection: [q_nope | q_rope], N=3072, grid 24x24=576
    gemm_mfma<<<dim3(24, T_SEQ / 128), 256, 0, stream>>>(
        t1kv, wqn_t, nullptr, qnr, T_SEQ, 3072, QLORA, T1KV_LD, QLORA, QNR_LD, 0);
    rope_q<<<(T_SEQ * NH * 32 + 255) / 256, 256, 0, stream>>>(qnr + NH * NOPE, freqs);

    // kv up-projection, grid 32x24=768
    gemm_mfma<<<dim3(NH * 256 / 128, T_SEQ / 128), 256, 0, stream>>>(
        ckvn, wkvu_t, nullptr, kvu, T_SEQ, NH * 256, KVLORA, KVLORA, KVLORA, NH * 256, 0);

    // V transpose for attention B-operand
    vt_transp<<<dim3(T_SEQ / 32, VDIM / 32, NH), 256, 0, stream>>>(kvu, vt);

    // split-K attention + combine
    attn_v8<<<dim3(T_SEQ / 64, 4, NH), 256, 0, stream>>>(qnr, kvu, kr, vt, Opart, lpart);
    attn_combine<<<dim3(T_SEQ / 64, NH), 256, 0, stream>>>(Opart, lpart, ao);

    // output projection (fp32 out)
    gemm_mfma<<<dim3(DIM / 128, T_SEQ / 128), 256, 0, stream>>>(
        ao, wo_t, out, nullptr, T_SEQ, DIM, DIM, DIM, DIM, DIM, 1);
}